// Round 1
// baseline (992.628 us; speedup 1.0000x reference)
//
#include <hip/hip_runtime.h>
#include <math.h>

#define EPSBN 1e-5f

// ---- workspace layout (float offsets) --------------------------------------
#define OFF_Y     0          // attention output y            (4*1024*4*128)
#define OFF_Y1    2097152    // w1 conv output                (same)
#define OFF_Z     4194304    // z = bn(y1)+x                  (same)
#define OFF_BN1   6291456    // mean[1024], var[1024]
#define OFF_APRE  6293504    // sa pre-BN                     (4*4*4*128)
#define OFF_SAST  6301696    // mean[4], var[4]
#define OFF_A     6301704    // A matrix 68x1024 (parts rows 0..63, u rows 64..67)
#define OFF_NB    6371336    // reduced 68x512 (parts_r, u_r)
#define OFF_NODES 6406152    // nodes 4x16x512
#define OFF_QPG   6438920    // qt,pp,gg : 3x4x16x512
#define OFF_CAT   6537224    // cat 4x4x1024
#define OFF_OUT0  6553608    // out0 4x1024x4
#define OFF_AW    6569992    // sigmoid a, [b][n][t][p]       (8192)
#define WS_FLOATS 6578184

// ---- 1) non-local attention: y = softmax(gx gx^T) gx, per batch ------------
// grid 256 (4 batches x 64 row-blocks of 64), block 256
__global__ __launch_bounds__(256) void k_attn(const float* __restrict__ x, float* __restrict__ y)
{
    const int tid = threadIdx.x;
    const int bb = blockIdx.x >> 6;
    const int rb = blockIdx.x & 63;
    const float* gx = x + (size_t)bb * (4096 * 128);
    float* yo = y + (size_t)bb * (4096 * 128);

    __shared__ float Qs[64][132];
    __shared__ float Ks[64][132];
    __shared__ float Ps[64][66];

    #pragma unroll
    for (int it = 0; it < 8; ++it) {
        int e = (it * 256 + tid) * 4;
        int r = e >> 7, c = e & 127;
        *(float4*)&Qs[r][c] = *(const float4*)(gx + (size_t)(rb * 64 + r) * 128 + c);
    }

    const int rg = tid >> 4;   // rows 4*rg..+3
    const int cg = tid & 15;   // cols 4*cg..+3 ; p-slice 8*cg..+7

    float mrun[4], lrun[4], yacc[4][8];
    #pragma unroll
    for (int i = 0; i < 4; ++i) {
        mrun[i] = -1e30f; lrun[i] = 0.f;
        #pragma unroll
        for (int p = 0; p < 8; ++p) yacc[i][p] = 0.f;
    }
    __syncthreads();

    for (int tn = 0; tn < 64; ++tn) {
        #pragma unroll
        for (int it = 0; it < 8; ++it) {
            int e = (it * 256 + tid) * 4;
            int r = e >> 7, c = e & 127;
            *(float4*)&Ks[r][c] = *(const float4*)(gx + (size_t)(tn * 64 + r) * 128 + c);
        }
        __syncthreads();

        float s[4][4];
        #pragma unroll
        for (int i = 0; i < 4; ++i)
            #pragma unroll
            for (int j = 0; j < 4; ++j) s[i][j] = 0.f;

        for (int k4 = 0; k4 < 32; ++k4) {
            float4 q[4], kk[4];
            #pragma unroll
            for (int i = 0; i < 4; ++i) q[i] = *(const float4*)&Qs[4 * rg + i][4 * k4];
            #pragma unroll
            for (int j = 0; j < 4; ++j) kk[j] = *(const float4*)&Ks[4 * cg + j][4 * k4];
            #pragma unroll
            for (int i = 0; i < 4; ++i)
                #pragma unroll
                for (int j = 0; j < 4; ++j)
                    s[i][j] += q[i].x * kk[j].x + q[i].y * kk[j].y + q[i].z * kk[j].z + q[i].w * kk[j].w;
        }

        #pragma unroll
        for (int i = 0; i < 4; ++i) {
            float tm = fmaxf(fmaxf(s[i][0], s[i][1]), fmaxf(s[i][2], s[i][3]));
            #pragma unroll
            for (int off = 1; off < 16; off <<= 1) tm = fmaxf(tm, __shfl_xor(tm, off, 64));
            float mn = fmaxf(mrun[i], tm);
            float al = __expf(mrun[i] - mn);
            float ts = 0.f;
            #pragma unroll
            for (int j = 0; j < 4; ++j) { s[i][j] = __expf(s[i][j] - mn); ts += s[i][j]; }
            #pragma unroll
            for (int off = 1; off < 16; off <<= 1) ts += __shfl_xor(ts, off, 64);
            lrun[i] = lrun[i] * al + ts;
            mrun[i] = mn;
            #pragma unroll
            for (int p = 0; p < 8; ++p) yacc[i][p] *= al;
        }

        #pragma unroll
        for (int i = 0; i < 4; ++i)
            #pragma unroll
            for (int j = 0; j < 4; ++j) Ps[4 * rg + i][4 * cg + j] = s[i][j];
        __syncthreads();

        for (int j = 0; j < 64; ++j) {
            float4 v0 = *(const float4*)&Ks[j][8 * cg];
            float4 v1 = *(const float4*)&Ks[j][8 * cg + 4];
            #pragma unroll
            for (int i = 0; i < 4; ++i) {
                float pv = Ps[4 * rg + i][j];
                yacc[i][0] += pv * v0.x; yacc[i][1] += pv * v0.y;
                yacc[i][2] += pv * v0.z; yacc[i][3] += pv * v0.w;
                yacc[i][4] += pv * v1.x; yacc[i][5] += pv * v1.y;
                yacc[i][6] += pv * v1.z; yacc[i][7] += pv * v1.w;
            }
        }
        __syncthreads();
    }

    #pragma unroll
    for (int i = 0; i < 4; ++i) {
        float inv = 1.f / lrun[i];
        int r = rb * 64 + 4 * rg + i;
        float4 o0, o1;
        o0.x = yacc[i][0] * inv; o0.y = yacc[i][1] * inv; o0.z = yacc[i][2] * inv; o0.w = yacc[i][3] * inv;
        o1.x = yacc[i][4] * inv; o1.y = yacc[i][5] * inv; o1.z = yacc[i][6] * inv; o1.w = yacc[i][7] * inv;
        *(float4*)(yo + (size_t)r * 128 + 8 * cg)     = o0;
        *(float4*)(yo + (size_t)r * 128 + 8 * cg + 4) = o1;
    }
}

// ---- 2) y1[b,o,thw] = sum_c y[b,c,thw] * w1w[o,c]  (bias cancels in BN) ----
// grid 256 = 16 o-tiles x 16 pos-tiles, block 256
__global__ __launch_bounds__(256) void k_w1(const float* __restrict__ y, const float* __restrict__ w1w,
                                            float* __restrict__ y1)
{
    const int tid = threadIdx.x;
    const int ot = blockIdx.x >> 4;
    const int pt = blockIdx.x & 15;
    const int b = pt >> 2;
    const int thw0 = (pt & 3) * 128;

    __shared__ float Ws[64][33];
    __shared__ float Ys[32][128];

    const int og = tid >> 5;
    const int pl = tid & 31;

    float acc[8][4];
    #pragma unroll
    for (int i = 0; i < 8; ++i)
        #pragma unroll
        for (int k = 0; k < 4; ++k) acc[i][k] = 0.f;

    for (int c0 = 0; c0 < 1024; c0 += 32) {
        #pragma unroll
        for (int it = 0; it < 8; ++it) {
            int e = it * 256 + tid;
            Ws[e >> 5][e & 31] = w1w[(size_t)(ot * 64 + (e >> 5)) * 1024 + c0 + (e & 31)];
        }
        #pragma unroll
        for (int it = 0; it < 4; ++it) {
            int e = (it * 256 + tid) * 4;
            int r = e >> 7, cc = e & 127;
            *(float4*)&Ys[r][cc] = *(const float4*)(y + (size_t)(b * 1024 + c0 + r) * 512 + thw0 + cc);
        }
        __syncthreads();
        #pragma unroll
        for (int cc = 0; cc < 32; ++cc) {
            float y0 = Ys[cc][pl], y1v = Ys[cc][pl + 32], y2v = Ys[cc][pl + 64], y3v = Ys[cc][pl + 96];
            #pragma unroll
            for (int i = 0; i < 8; ++i) {
                float w = Ws[og * 8 + i][cc];
                acc[i][0] += w * y0; acc[i][1] += w * y1v; acc[i][2] += w * y2v; acc[i][3] += w * y3v;
            }
        }
        __syncthreads();
    }
    #pragma unroll
    for (int i = 0; i < 8; ++i) {
        int o = ot * 64 + og * 8 + i;
        #pragma unroll
        for (int k = 0; k < 4; ++k)
            y1[(size_t)(b * 1024 + o) * 512 + thw0 + pl + 32 * k] = acc[i][k];
    }
}

// ---- 3) BN stats over (b,t,h,w)=2048 per channel ---------------------------
__global__ __launch_bounds__(256) void k_bnstat1(const float* __restrict__ y1, float* __restrict__ stat)
{
    const int o = blockIdx.x;
    const int tid = threadIdx.x;
    float s = 0.f, q = 0.f;
    #pragma unroll
    for (int it = 0; it < 8; ++it) {
        int e = it * 256 + tid;
        int b = e >> 9, j = e & 511;
        float v = y1[(size_t)(b * 1024 + o) * 512 + j];
        s += v; q += v * v;
    }
    #pragma unroll
    for (int off = 32; off > 0; off >>= 1) { s += __shfl_down(s, off, 64); q += __shfl_down(q, off, 64); }
    __shared__ float ss[4], qq[4];
    if ((tid & 63) == 0) { ss[tid >> 6] = s; qq[tid >> 6] = q; }
    __syncthreads();
    if (tid == 0) {
        float S = ss[0] + ss[1] + ss[2] + ss[3];
        float Q = qq[0] + qq[1] + qq[2] + qq[3];
        float m = S * (1.f / 2048.f);
        stat[o] = m;
        stat[1024 + o] = Q * (1.f / 2048.f) - m * m;
    }
}

// ---- 4) z = bn(y1)+x ; u[b,c] = mean_thw(z) into A rows 64..67 -------------
// grid 4096 (b*1024+o), block 128
__global__ __launch_bounds__(128) void k_zu(const float* __restrict__ y1, const float* __restrict__ x,
                                            const float* __restrict__ stat, const float* __restrict__ g,
                                            const float* __restrict__ beta, float* __restrict__ z,
                                            float* __restrict__ A)
{
    const int blk = blockIdx.x;
    const int b = blk >> 10, o = blk & 1023;
    const int tid = threadIdx.x;
    float rs = rsqrtf(stat[1024 + o] + EPSBN) * g[o];
    float bt = beta[o] - stat[o] * rs;
    size_t base = (size_t)blk * 512;
    float sum = 0.f;
    #pragma unroll
    for (int it = 0; it < 4; ++it) {
        int j = it * 128 + tid;
        float v = y1[base + j] * rs + bt + x[base + j];
        z[base + j] = v;
        sum += v;
    }
    #pragma unroll
    for (int off = 32; off > 0; off >>= 1) sum += __shfl_down(sum, off, 64);
    __shared__ float red[2];
    if ((tid & 63) == 0) red[tid >> 6] = sum;
    __syncthreads();
    if (tid == 0) A[(size_t)(64 + b) * 1024 + o] = (red[0] + red[1]) * (1.f / 512.f);
}

// ---- 5) spatial-attn pre-BN: apre[b,n,t,p] = sum_c z * sa_w[n,c] -----------
// grid 16 (b*4+t), block 256
__global__ __launch_bounds__(256) void k_sa(const float* __restrict__ z, const float* __restrict__ saw,
                                            float* __restrict__ apre)
{
    const int b = blockIdx.x >> 2, t = blockIdx.x & 3;
    const int tid = threadIdx.x;
    __shared__ float wsm[4][1024];
    __shared__ float part[2][4][128];
    #pragma unroll
    for (int it = 0; it < 16; ++it) {
        int e = it * 256 + tid;
        wsm[e >> 10][e & 1023] = saw[e];
    }
    __syncthreads();
    const int p = tid & 127, half = tid >> 7;
    float a0 = 0, a1 = 0, a2 = 0, a3 = 0;
    for (int ci = half * 512; ci < half * 512 + 512; ++ci) {
        float zv = z[(size_t)(b * 1024 + ci) * 512 + t * 128 + p];
        a0 += zv * wsm[0][ci]; a1 += zv * wsm[1][ci];
        a2 += zv * wsm[2][ci]; a3 += zv * wsm[3][ci];
    }
    part[half][0][p] = a0; part[half][1][p] = a1;
    part[half][2][p] = a2; part[half][3][p] = a3;
    __syncthreads();
    #pragma unroll
    for (int it = 0; it < 2; ++it) {
        int e = it * 256 + tid;
        int n = e >> 7, pp = e & 127;
        apre[(size_t)((b * 4 + n) * 4 + t) * 128 + pp] = part[0][n][pp] + part[1][n][pp];
    }
}

// ---- 6) sa BN stats (per n over 2048) --------------------------------------
__global__ __launch_bounds__(256) void k_sastat(const float* __restrict__ apre, float* __restrict__ stat)
{
    const int n = blockIdx.x;
    const int tid = threadIdx.x;
    float s = 0.f, q = 0.f;
    #pragma unroll
    for (int it = 0; it < 8; ++it) {
        int e = it * 256 + tid;
        int bt = e >> 7, p = e & 127;
        int b = bt >> 2, t = bt & 3;
        float v = apre[(size_t)((b * 4 + n) * 4 + t) * 128 + p];
        s += v; q += v * v;
    }
    #pragma unroll
    for (int off = 32; off > 0; off >>= 1) { s += __shfl_down(s, off, 64); q += __shfl_down(q, off, 64); }
    __shared__ float ss[4], qq[4];
    if ((tid & 63) == 0) { ss[tid >> 6] = s; qq[tid >> 6] = q; }
    __syncthreads();
    if (tid == 0) {
        float S = ss[0] + ss[1] + ss[2] + ss[3];
        float Q = qq[0] + qq[1] + qq[2] + qq[3];
        float m = S * (1.f / 2048.f);
        stat[n] = m;
        stat[4 + n] = Q * (1.f / 2048.f) - m * m;
    }
}

// ---- 7) a = sigmoid(bn(apre)); write ws copy + a_out -----------------------
__global__ __launch_bounds__(256) void k_saapply(const float* __restrict__ apre, const float* __restrict__ stat,
                                                 const float* __restrict__ sag, const float* __restrict__ sabeta,
                                                 float* __restrict__ aw, float* __restrict__ aout)
{
    int e = blockIdx.x * 256 + threadIdx.x;   // 8192
    int p = e & 127, t = (e >> 7) & 3, n = (e >> 9) & 3, b = e >> 11;
    float val = (apre[e] - stat[n]) * rsqrtf(stat[4 + n] + EPSBN) * sag[n] + sabeta[n];
    float sig = 1.f / (1.f + __expf(-val));
    aw[e] = sig;
    aout[(size_t)((b * 4 + t) * 4 + n) * 128 + p] = sig;
}

// ---- 8) parts[b,t,n,c] = sum_p a[n,p] z[c,p] into A rows 0..63 -------------
// grid 16 (b*4+t), block 256
__global__ __launch_bounds__(256) void k_parts(const float* __restrict__ z, const float* __restrict__ aw,
                                               float* __restrict__ A)
{
    const int b = blockIdx.x >> 2, t = blockIdx.x & 3;
    const int tid = threadIdx.x;
    __shared__ float As[4][132];
    __shared__ float Zs[64][132];
    #pragma unroll
    for (int it = 0; it < 2; ++it) {
        int e = it * 256 + tid;
        int n = e >> 7, p = e & 127;
        As[n][p] = aw[(size_t)((b * 4 + n) * 4 + t) * 128 + p];
    }
    const int cl = tid >> 2, n = tid & 3;
    for (int c0 = 0; c0 < 1024; c0 += 64) {
        #pragma unroll
        for (int it = 0; it < 8; ++it) {
            int e = (it * 256 + tid) * 4;
            int r = e >> 7, cc = e & 127;
            *(float4*)&Zs[r][cc] = *(const float4*)(z + (size_t)(b * 1024 + c0 + r) * 512 + t * 128 + cc);
        }
        __syncthreads();
        float acc = 0.f;
        #pragma unroll
        for (int k4 = 0; k4 < 32; ++k4) {
            float4 zv = *(const float4*)&Zs[cl][4 * k4];
            float4 av = *(const float4*)&As[n][4 * k4];
            acc += zv.x * av.x + zv.y * av.y + zv.z * av.z + zv.w * av.w;
        }
        A[(size_t)(b * 16 + t * 4 + n) * 1024 + c0 + cl] = acc;
        __syncthreads();
    }
}

// ---- 9) reduce_dimension: NB[68][512] = A[68][1024] @ g_w^T + g_b ----------
// grid 136, block 256
__global__ __launch_bounds__(256) void k_rd(const float* __restrict__ A, const float* __restrict__ gw,
                                            const float* __restrict__ gb, float* __restrict__ NB)
{
    int flat = blockIdx.x * 256 + threadIdx.x;   // 0..34815
    int row = flat >> 9, o = flat & 511;
    const float4* a4 = (const float4*)(A + (size_t)row * 1024);
    const float4* w4 = (const float4*)(gw + (size_t)o * 1024);
    float acc = 0.f;
    for (int k = 0; k < 256; ++k) {
        float4 av = a4[k], wv = w4[k];
        acc += av.x * wv.x + av.y * wv.y + av.z * wv.z + av.w * wv.w;
    }
    NB[flat] = acc + gb[o];
}

// ---- 10) nodes[b,j,o] = parts_r + (u_r @ wu)[o] ----------------------------
// grid 4, block 256
__global__ __launch_bounds__(256) void k_nodes(const float* __restrict__ NB, const float* __restrict__ wu,
                                               float* __restrict__ nodes)
{
    const int b = blockIdx.x;
    const int tid = threadIdx.x;
    __shared__ float us[512];
    __shared__ float uwu[512];
    us[tid] = NB[(size_t)(64 + b) * 512 + tid];
    us[tid + 256] = NB[(size_t)(64 + b) * 512 + tid + 256];
    __syncthreads();
    #pragma unroll
    for (int hh = 0; hh < 2; ++hh) {
        int o = hh * 256 + tid;
        float acc = 0.f;
        for (int k = 0; k < 512; ++k) acc += us[k] * wu[(size_t)k * 512 + o];
        uwu[o] = acc;
    }
    __syncthreads();
    #pragma unroll
    for (int it = 0; it < 32; ++it) {
        int e = it * 256 + tid;
        nodes[(size_t)b * 8192 + e] = NB[(size_t)b * 8192 + e] + uwu[e & 511];
    }
}

// ---- 11) qt/pp/gg = nodes @ {wt,wp,wg} -------------------------------------
// grid 48 (b x mat x o-chunk128), block 256
__global__ __launch_bounds__(256) void k_qpg(const float* __restrict__ nodes, const float* __restrict__ wt,
                                             const float* __restrict__ wp, const float* __restrict__ wg,
                                             float* __restrict__ qpg)
{
    const int b = blockIdx.x / 12;
    const int r = blockIdx.x % 12;
    const int m = r >> 2;
    const int o0 = (r & 3) * 128;
    const float* W = (m == 0) ? wt : (m == 1) ? wp : wg;
    const int tid = threadIdx.x;
    __shared__ float ns[16][512];
    #pragma unroll
    for (int it = 0; it < 32; ++it) {
        int e = it * 256 + tid;
        ns[e >> 9][e & 511] = nodes[(size_t)b * 8192 + e];
    }
    __syncthreads();
    const int o = o0 + (tid & 127);
    const int jg = tid >> 7;
    float acc[8];
    #pragma unroll
    for (int jj = 0; jj < 8; ++jj) acc[jj] = 0.f;
    for (int k4 = 0; k4 < 128; ++k4) {
        float w0 = W[(size_t)(4 * k4 + 0) * 512 + o];
        float w1 = W[(size_t)(4 * k4 + 1) * 512 + o];
        float w2 = W[(size_t)(4 * k4 + 2) * 512 + o];
        float w3 = W[(size_t)(4 * k4 + 3) * 512 + o];
        #pragma unroll
        for (int jj = 0; jj < 8; ++jj) {
            float4 nv = *(const float4*)&ns[jg * 8 + jj][4 * k4];
            acc[jj] += nv.x * w0 + nv.y * w1 + nv.z * w2 + nv.w * w3;
        }
    }
    #pragma unroll
    for (int jj = 0; jj < 8; ++jj)
        qpg[(size_t)((m * 4 + b) * 16 + jg * 8 + jj) * 512 + o] = acc[jj];
}

// ---- 12) STIAU attention + aggregate + cat ---------------------------------
// grid 4, block 256
__global__ __launch_bounds__(256) void k_stiau(const float* __restrict__ nodes, const float* __restrict__ qpg,
                                               const float* __restrict__ NB, float* __restrict__ cat)
{
    const int b = blockIdx.x;
    const int tid = threadIdx.x;
    __shared__ float q_s[16][516];
    __shared__ float p_s[16][516];
    __shared__ float att[16][17];
    #pragma unroll
    for (int it = 0; it < 32; ++it) {
        int e = it * 256 + tid;
        int j = e >> 9, k = e & 511;
        q_s[j][k] = qpg[(size_t)(0 * 4 + b) * 8192 + e];
        p_s[j][k] = qpg[(size_t)(1 * 4 + b) * 8192 + e];
    }
    __syncthreads();
    const int j = tid >> 4, mm = tid & 15;
    float acc = 0.f;
    #pragma unroll
    for (int k4 = 0; k4 < 128; ++k4) {
        float4 qv = *(const float4*)&q_s[j][4 * k4];
        float4 pv = *(const float4*)&p_s[mm][4 * k4];
        acc += qv.x * pv.x + qv.y * pv.y + qv.z * pv.z + qv.w * pv.w;
    }
    acc *= 0.04419417382415922f;   // 1/sqrt(512)
    float mx = acc;
    #pragma unroll
    for (int off = 1; off < 16; off <<= 1) mx = fmaxf(mx, __shfl_xor(mx, off, 64));
    float ev = __expf(acc - mx);
    float sm = ev;
    #pragma unroll
    for (int off = 1; off < 16; off <<= 1) sm += __shfl_xor(sm, off, 64);
    att[j][mm] = ev / sm;
    __syncthreads();
    #pragma unroll
    for (int it = 0; it < 32; ++it) {        // load gg into q_s
        int e = it * 256 + tid;
        q_s[e >> 9][e & 511] = qpg[(size_t)(2 * 4 + b) * 8192 + e];
    }
    __syncthreads();
    #pragma unroll
    for (int it = 0; it < 32; ++it) {        // nodes2 into p_s
        int e = it * 256 + tid;
        int jj = e >> 9, o = e & 511;
        float v = nodes[(size_t)b * 8192 + e];
        #pragma unroll
        for (int m2 = 0; m2 < 16; ++m2) v += att[jj][m2] * q_s[m2][o];
        p_s[jj][o] = v;
    }
    __syncthreads();
    #pragma unroll
    for (int it = 0; it < 16; ++it) {
        int e = it * 256 + tid;   // 0..4095
        int t = e >> 10, cc = e & 1023;
        float val;
        if (cc < 512)
            val = 0.25f * (p_s[t * 4 + 0][cc] + p_s[t * 4 + 1][cc] + p_s[t * 4 + 2][cc] + p_s[t * 4 + 3][cc]);
        else
            val = NB[(size_t)(64 + b) * 512 + (cc - 512)];
        cat[(size_t)(b * 4 + t) * 1024 + cc] = val;
    }
}

// ---- 13) out0[b,o,t] = cat[b,t,:] . w2_w[o,:]  (bias cancels in BN) --------
// grid 64, block 256
__global__ __launch_bounds__(256) void k_w2(const float* __restrict__ cat, const float* __restrict__ w2w,
                                            float* __restrict__ out0)
{
    int flat = blockIdx.x * 256 + threadIdx.x;  // 16384 = b*4096 + o*4 + t
    int b = flat >> 12, o = (flat >> 2) & 1023, t = flat & 3;
    const float4* c4 = (const float4*)(cat + (size_t)(b * 4 + t) * 1024);
    const float4* w4 = (const float4*)(w2w + (size_t)o * 1024);
    float acc = 0.f;
    for (int k = 0; k < 256; ++k) {
        float4 cv = c4[k], wv = w4[k];
        acc += cv.x * wv.x + cv.y * wv.y + cv.z * wv.z + cv.w * wv.w;
    }
    out0[flat] = acc;
}

// ---- 14) BN over (b,t)=16 per channel; z_out = bn(out0) + z ----------------
// grid 1024 (o), block 256
__global__ __launch_bounds__(256) void k_bn2out(const float* __restrict__ out0, const float* __restrict__ g,
                                                const float* __restrict__ beta, const float* __restrict__ z,
                                                float* __restrict__ zout)
{
    const int o = blockIdx.x;
    const int tid = threadIdx.x;
    __shared__ float bnv[16];
    if (tid == 0) {
        float s = 0.f, q = 0.f, vals[16];
        #pragma unroll
        for (int i = 0; i < 16; ++i) {
            int b = i >> 2, t = i & 3;
            float v = out0[(size_t)(b * 1024 + o) * 4 + t];
            vals[i] = v; s += v; q += v * v;
        }
        float m = s * (1.f / 16.f);
        float var = q * (1.f / 16.f) - m * m;
        float rs = rsqrtf(var + EPSBN) * g[o];
        float bb = beta[o] - m * rs;
        #pragma unroll
        for (int i = 0; i < 16; ++i) bnv[i] = vals[i] * rs + bb;
    }
    __syncthreads();
    #pragma unroll
    for (int it = 0; it < 8; ++it) {
        int e = it * 256 + tid;     // bt*128 + p
        int bt = e >> 7, p = e & 127;
        int b = bt >> 2, t = bt & 3;
        size_t idx = (size_t)(b * 1024 + o) * 512 + t * 128 + p;
        zout[idx] = z[idx] + bnv[bt];
    }
}

extern "C" void kernel_launch(void* const* d_in, const int* in_sizes, int n_in,
                              void* d_out, int out_size, void* d_ws, size_t ws_size,
                              hipStream_t stream)
{
    const float* x      = (const float*)d_in[0];
    const float* sa_w   = (const float*)d_in[1];
    // d_in[2] sa_b: cancels in BN
    const float* sa_g   = (const float*)d_in[3];
    const float* sa_be  = (const float*)d_in[4];
    const float* g_w    = (const float*)d_in[5];
    const float* g_b    = (const float*)d_in[6];
    const float* w1_w   = (const float*)d_in[7];
    // d_in[8] w1_b: cancels in BN
    const float* w1_g   = (const float*)d_in[9];
    const float* w1_be  = (const float*)d_in[10];
    const float* w2_w   = (const float*)d_in[11];
    // d_in[12] w2_b: cancels in BN
    const float* w2_g   = (const float*)d_in[13];
    const float* w2_be  = (const float*)d_in[14];
    const float* wt     = (const float*)d_in[15];
    const float* wp     = (const float*)d_in[16];
    const float* wg     = (const float*)d_in[17];
    const float* wu     = (const float*)d_in[18];
    float* out = (float*)d_out;
    float* ws  = (float*)d_ws;
    if (ws_size < (size_t)WS_FLOATS * sizeof(float)) return;  // fail loudly (d_out stays poisoned)

    float* Y    = ws + OFF_Y;
    float* Y1   = ws + OFF_Y1;
    float* Z    = ws + OFF_Z;
    float* BN1  = ws + OFF_BN1;
    float* APRE = ws + OFF_APRE;
    float* SAST = ws + OFF_SAST;
    float* A    = ws + OFF_A;
    float* NBm  = ws + OFF_NB;
    float* NOD  = ws + OFF_NODES;
    float* QPG  = ws + OFF_QPG;
    float* CAT  = ws + OFF_CAT;
    float* OUT0 = ws + OFF_OUT0;
    float* AW   = ws + OFF_AW;
    float* AOUT = out + 2097152;

    hipLaunchKernelGGL(k_attn,    dim3(256),  dim3(256), 0, stream, x, Y);
    hipLaunchKernelGGL(k_w1,      dim3(256),  dim3(256), 0, stream, Y, w1_w, Y1);
    hipLaunchKernelGGL(k_bnstat1, dim3(1024), dim3(256), 0, stream, Y1, BN1);
    hipLaunchKernelGGL(k_zu,      dim3(4096), dim3(128), 0, stream, Y1, x, BN1, w1_g, w1_be, Z, A);
    hipLaunchKernelGGL(k_sa,      dim3(16),   dim3(256), 0, stream, Z, sa_w, APRE);
    hipLaunchKernelGGL(k_sastat,  dim3(4),    dim3(256), 0, stream, APRE, SAST);
    hipLaunchKernelGGL(k_saapply, dim3(32),   dim3(256), 0, stream, APRE, SAST, sa_g, sa_be, AW, AOUT);
    hipLaunchKernelGGL(k_parts,   dim3(16),   dim3(256), 0, stream, Z, AW, A);
    hipLaunchKernelGGL(k_rd,      dim3(136),  dim3(256), 0, stream, A, g_w, g_b, NBm);
    hipLaunchKernelGGL(k_nodes,   dim3(4),    dim3(256), 0, stream, NBm, wu, NOD);
    hipLaunchKernelGGL(k_qpg,     dim3(48),   dim3(256), 0, stream, NOD, wt, wp, wg, QPG);
    hipLaunchKernelGGL(k_stiau,   dim3(4),    dim3(256), 0, stream, NOD, QPG, NBm, CAT);
    hipLaunchKernelGGL(k_w2,      dim3(64),   dim3(256), 0, stream, CAT, w2_w, OUT0);
    hipLaunchKernelGGL(k_bn2out,  dim3(1024), dim3(256), 0, stream, OUT0, w2_g, w2_be, Z, out);
}

// Round 2
// 452.089 us; speedup vs baseline: 2.1956x; 2.1956x over previous
//
#include <hip/hip_runtime.h>
#include <math.h>

#define EPSBN 1e-5f

typedef __attribute__((ext_vector_type(4))) float f32x4;
typedef __attribute__((ext_vector_type(8))) short short8v;
typedef __attribute__((ext_vector_type(4))) short short4v;

__device__ __forceinline__ short f2bf(float f) {
    unsigned u = __float_as_uint(f);
    u = (u + 0x7FFFu + ((u >> 16) & 1u)) >> 16;
    return (short)u;
}

// ---- workspace layout (float offsets) --------------------------------------
#define OFF_Y     0          // attention output y            (4*1024*4*128)
#define OFF_Y1    2097152    // w1 conv output                (same)
#define OFF_Z     4194304    // z = bn(y1)+x                  (same)
#define OFF_BN1   6291456    // mean[1024], var[1024]
#define OFF_APRE  6293504    // sa pre-BN                     (4*4*4*128)
#define OFF_SAST  6301696    // mean[4], var[4]
#define OFF_A     6301704    // A matrix 68x1024 (parts rows 0..63, u rows 64..67)
#define OFF_NB    6371336    // reduced 68x512 (parts_r, u_r)
#define OFF_NODES 6406152    // nodes 4x16x512
#define OFF_QPG   6438920    // qt,pp,gg : 3x4x16x512
#define OFF_CAT   6537224    // cat 4x4x1024
#define OFF_OUT0  6553608    // out0 4x1024x4
#define OFF_AW    6569992    // sigmoid a, [b][n][t][p]       (8192)
#define WS_FLOATS 6578184

// ---- 1) non-local attention via bf16 MFMA flash -----------------------------
// grid 256, block 256 (4 waves x 16 Q-rows = 64 Q-rows/block)
// K/V tile (same data) staged once per 64-KV tile in LDS, subtiled [8][64][16]
// (+16-elem pad/subtile -> staging writes conflict-free). QK^T B-frags via
// ds_read_b128; PV V-column access via ds_read_b64_tr_b16.
#define SUBT 1040            // padded subtile stride, elems (64*16 + 16)
#define KBUF (8 * SUBT)

__global__ __launch_bounds__(256, 1) void k_attn_mfma(const float* __restrict__ x,
                                                      float* __restrict__ y)
{
    __shared__ short Ks[2][KBUF];      // 33280 B
    __shared__ short Pl[4][16 * 72];   //  9216 B

    const int tid  = threadIdx.x;
    const int lane = tid & 63;
    const int wid  = tid >> 6;
    const int g    = lane >> 4;
    const int c15  = lane & 15;

    // XCD-aware decode: xcd = bid&7 (dispatch heuristic), 2 XCDs per batch ->
    // each XCD L2 caches one batch's 2MB gx.
    const int bswz = blockIdx.x;
    const int xcd  = bswz & 7;
    const int bb   = xcd >> 1;
    const int rb   = ((bswz >> 3) << 1) | (xcd & 1);

    const float* gx = x + (size_t)bb * (4096 * 128);
    float*       yo = y + (size_t)bb * (4096 * 128);

    // ---- Q fragments: lane holds Q[qrow0 + (lane&15)][8*(lane>>4) + j + 32*kc]
    const int qrow0 = rb * 64 + wid * 16;
    short8v qf[4];
    {
        const float* qp = gx + (size_t)(qrow0 + c15) * 128 + 8 * g;
        #pragma unroll
        for (int kc = 0; kc < 4; ++kc) {
            float4 a = *(const float4*)(qp + kc * 32);
            float4 b = *(const float4*)(qp + kc * 32 + 4);
            short8v q;
            q[0] = f2bf(a.x); q[1] = f2bf(a.y); q[2] = f2bf(a.z); q[3] = f2bf(a.w);
            q[4] = f2bf(b.x); q[5] = f2bf(b.y); q[6] = f2bf(b.z); q[7] = f2bf(b.w);
            qf[kc] = q;
        }
    }

    f32x4 yacc[8];
    const f32x4 z4 = {0.f, 0.f, 0.f, 0.f};
    #pragma unroll
    for (int dt = 0; dt < 8; ++dt) yacc[dt] = z4;
    float mrun[4] = {-1e30f, -1e30f, -1e30f, -1e30f};
    float lrun[4] = {0.f, 0.f, 0.f, 0.f};

    // QK B-frag lane-invariant offset: row = 16*nt + c15, k = 32*kc + 8*g
    const int qkb = (g >> 1) * SUBT + c15 * 16 + (g & 1) * 8;
    // tr-read per-lane byte offset (within buffer): row = kcp*32+8g+(c15>>2), col4 = 4*(c15&3)
    const unsigned trL = (unsigned)((8 * g + (c15 >> 2)) * 32 + (c15 & 3) * 8);

    // ---- stage tile 0 ----
    {
        #pragma unroll
        for (int it = 0; it < 8; ++it) {
            int e = (it * 256 + tid) * 4;
            float4 v = *(const float4*)(gx + e);
            int r = e >> 7, c = e & 127;
            short4v w;
            w[0] = f2bf(v.x); w[1] = f2bf(v.y); w[2] = f2bf(v.z); w[3] = f2bf(v.w);
            *(short4v*)&Ks[0][(c >> 4) * SUBT + r * 16 + (c & 15)] = w;
        }
    }
    __syncthreads();

    int cur = 0;
    for (int tn = 0; tn < 64; ++tn) {
        // issue global loads for next tile (consumed after compute -> latency hidden)
        float4 ld[8];
        if (tn < 63) {
            const float* src = gx + (size_t)(tn + 1) * 8192;
            #pragma unroll
            for (int it = 0; it < 8; ++it)
                ld[it] = *(const float4*)(src + (it * 256 + tid) * 4);
        }

        // ---- QK^T: S tile 16x64 per wave ----
        f32x4 sacc[4];
        #pragma unroll
        for (int nt = 0; nt < 4; ++nt) sacc[nt] = z4;
        {
            const short* kb = &Ks[cur][0];
            #pragma unroll
            for (int kc = 0; kc < 4; ++kc) {
                #pragma unroll
                for (int nt = 0; nt < 4; ++nt) {
                    short8v bf = *(const short8v*)&kb[qkb + kc * (2 * SUBT) + nt * 256];
                    sacc[nt] = __builtin_amdgcn_mfma_f32_16x16x32_bf16(qf[kc], bf, sacc[nt], 0, 0, 0);
                }
            }
        }

        // ---- online softmax (rows 4*g+rg; 16 lanes/group share rows) ----
        float tm[4]; int upd = 0;
        #pragma unroll
        for (int rg = 0; rg < 4; ++rg) {
            float v = fmaxf(fmaxf(sacc[0][rg], sacc[1][rg]), fmaxf(sacc[2][rg], sacc[3][rg]));
            v = fmaxf(v, __shfl_xor(v, 1, 64));
            v = fmaxf(v, __shfl_xor(v, 2, 64));
            v = fmaxf(v, __shfl_xor(v, 4, 64));
            v = fmaxf(v, __shfl_xor(v, 8, 64));
            tm[rg] = v;
            upd |= (v > mrun[rg]) ? 1 : 0;
        }
        if (__any(upd)) {   // rare: softmax is diagonal-peaked
            #pragma unroll
            for (int rg = 0; rg < 4; ++rg) {
                float mn = fmaxf(mrun[rg], tm[rg]);
                float al = __expf(mrun[rg] - mn);
                mrun[rg] = mn;
                lrun[rg] *= al;
                #pragma unroll
                for (int dt = 0; dt < 8; ++dt) yacc[dt][rg] *= al;
            }
        }
        #pragma unroll
        for (int rg = 0; rg < 4; ++rg) {
            float p0 = __expf(sacc[0][rg] - mrun[rg]);
            float p1 = __expf(sacc[1][rg] - mrun[rg]);
            float p2 = __expf(sacc[2][rg] - mrun[rg]);
            float p3 = __expf(sacc[3][rg] - mrun[rg]);
            short* pw = &Pl[wid][(4 * g + rg) * 72 + c15];
            pw[0]  = f2bf(p0);
            pw[16] = f2bf(p1);
            pw[32] = f2bf(p2);
            pw[48] = f2bf(p3);
            float ts = p0 + p1 + p2 + p3;
            ts += __shfl_xor(ts, 1, 64);
            ts += __shfl_xor(ts, 2, 64);
            ts += __shfl_xor(ts, 4, 64);
            ts += __shfl_xor(ts, 8, 64);
            lrun[rg] += ts;
        }

        // ---- PV: Y += P(16x64) * V(64x128), V = same staged tile ----
        {
            unsigned kbase = (unsigned)(size_t)&Ks[cur][0];
            unsigned trbase = kbase + trL;
            #pragma unroll
            for (int kcp = 0; kcp < 2; ++kcp) {
                short8v pa = *(const short8v*)&Pl[wid][c15 * 72 + kcp * 32 + 8 * g];
                unsigned long long lo[8], hi[8];
                #pragma unroll
                for (int dt = 0; dt < 8; ++dt) {
                    unsigned a = trbase + (unsigned)(kcp * 1024 + dt * (2 * SUBT));
                    asm volatile("ds_read_b64_tr_b16 %0, %1" : "=v"(lo[dt]) : "v"(a));
                    asm volatile("ds_read_b64_tr_b16 %0, %1 offset:128" : "=v"(hi[dt]) : "v"(a));
                }
                asm volatile("s_waitcnt lgkmcnt(0)" ::: "memory");
                __builtin_amdgcn_sched_barrier(0);
                #pragma unroll
                for (int dt = 0; dt < 8; ++dt) {
                    union { unsigned long long u[2]; short8v s; } fr;
                    fr.u[0] = lo[dt]; fr.u[1] = hi[dt];
                    yacc[dt] = __builtin_amdgcn_mfma_f32_16x16x32_bf16(pa, fr.s, yacc[dt], 0, 0, 0);
                }
            }
        }

        // ---- write staged next tile, flip buffers ----
        if (tn < 63) {
            #pragma unroll
            for (int it = 0; it < 8; ++it) {
                int e = (it * 256 + tid) * 4;
                int r = e >> 7, c = e & 127;
                short4v w;
                w[0] = f2bf(ld[it].x); w[1] = f2bf(ld[it].y);
                w[2] = f2bf(ld[it].z); w[3] = f2bf(ld[it].w);
                *(short4v*)&Ks[cur ^ 1][(c >> 4) * SUBT + r * 16 + (c & 15)] = w;
            }
        }
        __syncthreads();
        cur ^= 1;
    }

    // ---- epilogue: Y /= l ----
    #pragma unroll
    for (int rg = 0; rg < 4; ++rg) {
        float inv = 1.f / lrun[rg];
        float* yr = yo + (size_t)(qrow0 + 4 * g + rg) * 128 + c15;
        #pragma unroll
        for (int dt = 0; dt < 8; ++dt)
            yr[16 * dt] = yacc[dt][rg] * inv;
    }
}

// ---- 2) y1[b,o,thw] = sum_c y[b,c,thw] * w1w[o,c]  (bias cancels in BN) ----
// grid 256 = 16 o-tiles x 16 pos-tiles, block 256
__global__ __launch_bounds__(256) void k_w1(const float* __restrict__ y, const float* __restrict__ w1w,
                                            float* __restrict__ y1)
{
    const int tid = threadIdx.x;
    const int ot = blockIdx.x >> 4;
    const int pt = blockIdx.x & 15;
    const int b = pt >> 2;
    const int thw0 = (pt & 3) * 128;

    __shared__ float Ws[64][33];
    __shared__ float Ys[32][128];

    const int og = tid >> 5;
    const int pl = tid & 31;

    float acc[8][4];
    #pragma unroll
    for (int i = 0; i < 8; ++i)
        #pragma unroll
        for (int k = 0; k < 4; ++k) acc[i][k] = 0.f;

    for (int c0 = 0; c0 < 1024; c0 += 32) {
        #pragma unroll
        for (int it = 0; it < 8; ++it) {
            int e = it * 256 + tid;
            Ws[e >> 5][e & 31] = w1w[(size_t)(ot * 64 + (e >> 5)) * 1024 + c0 + (e & 31)];
        }
        #pragma unroll
        for (int it = 0; it < 4; ++it) {
            int e = (it * 256 + tid) * 4;
            int r = e >> 7, cc = e & 127;
            *(float4*)&Ys[r][cc] = *(const float4*)(y + (size_t)(b * 1024 + c0 + r) * 512 + thw0 + cc);
        }
        __syncthreads();
        #pragma unroll
        for (int cc = 0; cc < 32; ++cc) {
            float y0 = Ys[cc][pl], y1v = Ys[cc][pl + 32], y2v = Ys[cc][pl + 64], y3v = Ys[cc][pl + 96];
            #pragma unroll
            for (int i = 0; i < 8; ++i) {
                float w = Ws[og * 8 + i][cc];
                acc[i][0] += w * y0; acc[i][1] += w * y1v; acc[i][2] += w * y2v; acc[i][3] += w * y3v;
            }
        }
        __syncthreads();
    }
    #pragma unroll
    for (int i = 0; i < 8; ++i) {
        int o = ot * 64 + og * 8 + i;
        #pragma unroll
        for (int k = 0; k < 4; ++k)
            y1[(size_t)(b * 1024 + o) * 512 + thw0 + pl + 32 * k] = acc[i][k];
    }
}

// ---- 3) BN stats over (b,t,h,w)=2048 per channel ---------------------------
__global__ __launch_bounds__(256) void k_bnstat1(const float* __restrict__ y1, float* __restrict__ stat)
{
    const int o = blockIdx.x;
    const int tid = threadIdx.x;
    float s = 0.f, q = 0.f;
    #pragma unroll
    for (int it = 0; it < 8; ++it) {
        int e = it * 256 + tid;
        int b = e >> 9, j = e & 511;
        float v = y1[(size_t)(b * 1024 + o) * 512 + j];
        s += v; q += v * v;
    }
    #pragma unroll
    for (int off = 32; off > 0; off >>= 1) { s += __shfl_down(s, off, 64); q += __shfl_down(q, off, 64); }
    __shared__ float ss[4], qq[4];
    if ((tid & 63) == 0) { ss[tid >> 6] = s; qq[tid >> 6] = q; }
    __syncthreads();
    if (tid == 0) {
        float S = ss[0] + ss[1] + ss[2] + ss[3];
        float Q = qq[0] + qq[1] + qq[2] + qq[3];
        float m = S * (1.f / 2048.f);
        stat[o] = m;
        stat[1024 + o] = Q * (1.f / 2048.f) - m * m;
    }
}

// ---- 4) z = bn(y1)+x ; u[b,c] = mean_thw(z) into A rows 64..67 -------------
// grid 4096 (b*1024+o), block 128
__global__ __launch_bounds__(128) void k_zu(const float* __restrict__ y1, const float* __restrict__ x,
                                            const float* __restrict__ stat, const float* __restrict__ g,
                                            const float* __restrict__ beta, float* __restrict__ z,
                                            float* __restrict__ A)
{
    const int blk = blockIdx.x;
    const int b = blk >> 10, o = blk & 1023;
    const int tid = threadIdx.x;
    float rs = rsqrtf(stat[1024 + o] + EPSBN) * g[o];
    float bt = beta[o] - stat[o] * rs;
    size_t base = (size_t)blk * 512;
    float sum = 0.f;
    #pragma unroll
    for (int it = 0; it < 4; ++it) {
        int j = it * 128 + tid;
        float v = y1[base + j] * rs + bt + x[base + j];
        z[base + j] = v;
        sum += v;
    }
    #pragma unroll
    for (int off = 32; off > 0; off >>= 1) sum += __shfl_down(sum, off, 64);
    __shared__ float red[2];
    if ((tid & 63) == 0) red[tid >> 6] = sum;
    __syncthreads();
    if (tid == 0) A[(size_t)(64 + b) * 1024 + o] = (red[0] + red[1]) * (1.f / 512.f);
}

// ---- 5) spatial-attn pre-BN: apre[b,n,t,p] = sum_c z * sa_w[n,c] -----------
// grid 16 (b*4+t), block 256
__global__ __launch_bounds__(256) void k_sa(const float* __restrict__ z, const float* __restrict__ saw,
                                            float* __restrict__ apre)
{
    const int b = blockIdx.x >> 2, t = blockIdx.x & 3;
    const int tid = threadIdx.x;
    __shared__ float wsm[4][1024];
    __shared__ float part[2][4][128];
    #pragma unroll
    for (int it = 0; it < 16; ++it) {
        int e = it * 256 + tid;
        wsm[e >> 10][e & 1023] = saw[e];
    }
    __syncthreads();
    const int p = tid & 127, half = tid >> 7;
    float a0 = 0, a1 = 0, a2 = 0, a3 = 0;
    for (int ci = half * 512; ci < half * 512 + 512; ++ci) {
        float zv = z[(size_t)(b * 1024 + ci) * 512 + t * 128 + p];
        a0 += zv * wsm[0][ci]; a1 += zv * wsm[1][ci];
        a2 += zv * wsm[2][ci]; a3 += zv * wsm[3][ci];
    }
    part[half][0][p] = a0; part[half][1][p] = a1;
    part[half][2][p] = a2; part[half][3][p] = a3;
    __syncthreads();
    #pragma unroll
    for (int it = 0; it < 2; ++it) {
        int e = it * 256 + tid;
        int n = e >> 7, pp = e & 127;
        apre[(size_t)((b * 4 + n) * 4 + t) * 128 + pp] = part[0][n][pp] + part[1][n][pp];
    }
}

// ---- 6) sa BN stats (per n over 2048) --------------------------------------
__global__ __launch_bounds__(256) void k_sastat(const float* __restrict__ apre, float* __restrict__ stat)
{
    const int n = blockIdx.x;
    const int tid = threadIdx.x;
    float s = 0.f, q = 0.f;
    #pragma unroll
    for (int it = 0; it < 8; ++it) {
        int e = it * 256 + tid;
        int bt = e >> 7, p = e & 127;
        int b = bt >> 2, t = bt & 3;
        float v = apre[(size_t)((b * 4 + n) * 4 + t) * 128 + p];
        s += v; q += v * v;
    }
    #pragma unroll
    for (int off = 32; off > 0; off >>= 1) { s += __shfl_down(s, off, 64); q += __shfl_down(q, off, 64); }
    __shared__ float ss[4], qq[4];
    if ((tid & 63) == 0) { ss[tid >> 6] = s; qq[tid >> 6] = q; }
    __syncthreads();
    if (tid == 0) {
        float S = ss[0] + ss[1] + ss[2] + ss[3];
        float Q = qq[0] + qq[1] + qq[2] + qq[3];
        float m = S * (1.f / 2048.f);
        stat[n] = m;
        stat[4 + n] = Q * (1.f / 2048.f) - m * m;
    }
}

// ---- 7) a = sigmoid(bn(apre)); write ws copy + a_out -----------------------
__global__ __launch_bounds__(256) void k_saapply(const float* __restrict__ apre, const float* __restrict__ stat,
                                                 const float* __restrict__ sag, const float* __restrict__ sabeta,
                                                 float* __restrict__ aw, float* __restrict__ aout)
{
    int e = blockIdx.x * 256 + threadIdx.x;   // 8192
    int p = e & 127, t = (e >> 7) & 3, n = (e >> 9) & 3, b = e >> 11;
    float val = (apre[e] - stat[n]) * rsqrtf(stat[4 + n] + EPSBN) * sag[n] + sabeta[n];
    float sig = 1.f / (1.f + __expf(-val));
    aw[e] = sig;
    aout[(size_t)((b * 4 + t) * 4 + n) * 128 + p] = sig;
}

// ---- 8) parts[b,t,n,c] = sum_p a[n,p] z[c,p] into A rows 0..63 -------------
// grid 16 (b*4+t), block 256
__global__ __launch_bounds__(256) void k_parts(const float* __restrict__ z, const float* __restrict__ aw,
                                               float* __restrict__ A)
{
    const int b = blockIdx.x >> 2, t = blockIdx.x & 3;
    const int tid = threadIdx.x;
    __shared__ float As[4][132];
    __shared__ float Zs[64][132];
    #pragma unroll
    for (int it = 0; it < 2; ++it) {
        int e = it * 256 + tid;
        int n = e >> 7, p = e & 127;
        As[n][p] = aw[(size_t)((b * 4 + n) * 4 + t) * 128 + p];
    }
    const int cl = tid >> 2, n = tid & 3;
    for (int c0 = 0; c0 < 1024; c0 += 64) {
        #pragma unroll
        for (int it = 0; it < 8; ++it) {
            int e = (it * 256 + tid) * 4;
            int r = e >> 7, cc = e & 127;
            *(float4*)&Zs[r][cc] = *(const float4*)(z + (size_t)(b * 1024 + c0 + r) * 512 + t * 128 + cc);
        }
        __syncthreads();
        float acc = 0.f;
        #pragma unroll
        for (int k4 = 0; k4 < 32; ++k4) {
            float4 zv = *(const float4*)&Zs[cl][4 * k4];
            float4 av = *(const float4*)&As[n][4 * k4];
            acc += zv.x * av.x + zv.y * av.y + zv.z * av.z + zv.w * av.w;
        }
        A[(size_t)(b * 16 + t * 4 + n) * 1024 + c0 + cl] = acc;
        __syncthreads();
    }
}

// ---- 9) reduce_dimension: NB[68][512] = A[68][1024] @ g_w^T + g_b ----------
// grid 136, block 256
__global__ __launch_bounds__(256) void k_rd(const float* __restrict__ A, const float* __restrict__ gw,
                                            const float* __restrict__ gb, float* __restrict__ NB)
{
    int flat = blockIdx.x * 256 + threadIdx.x;   // 0..34815
    int row = flat >> 9, o = flat & 511;
    const float4* a4 = (const float4*)(A + (size_t)row * 1024);
    const float4* w4 = (const float4*)(gw + (size_t)o * 1024);
    float acc = 0.f;
    for (int k = 0; k < 256; ++k) {
        float4 av = a4[k], wv = w4[k];
        acc += av.x * wv.x + av.y * wv.y + av.z * wv.z + av.w * wv.w;
    }
    NB[flat] = acc + gb[o];
}

// ---- 10) nodes[b,j,o] = parts_r + (u_r @ wu)[o] ----------------------------
// grid 4, block 256
__global__ __launch_bounds__(256) void k_nodes(const float* __restrict__ NB, const float* __restrict__ wu,
                                               float* __restrict__ nodes)
{
    const int b = blockIdx.x;
    const int tid = threadIdx.x;
    __shared__ float us[512];
    __shared__ float uwu[512];
    us[tid] = NB[(size_t)(64 + b) * 512 + tid];
    us[tid + 256] = NB[(size_t)(64 + b) * 512 + tid + 256];
    __syncthreads();
    #pragma unroll
    for (int hh = 0; hh < 2; ++hh) {
        int o = hh * 256 + tid;
        float acc = 0.f;
        for (int k = 0; k < 512; ++k) acc += us[k] * wu[(size_t)k * 512 + o];
        uwu[o] = acc;
    }
    __syncthreads();
    #pragma unroll
    for (int it = 0; it < 32; ++it) {
        int e = it * 256 + tid;
        nodes[(size_t)b * 8192 + e] = NB[(size_t)b * 8192 + e] + uwu[e & 511];
    }
}

// ---- 11) qt/pp/gg = nodes @ {wt,wp,wg} -------------------------------------
// grid 48 (b x mat x o-chunk128), block 256
__global__ __launch_bounds__(256) void k_qpg(const float* __restrict__ nodes, const float* __restrict__ wt,
                                             const float* __restrict__ wp, const float* __restrict__ wg,
                                             float* __restrict__ qpg)
{
    const int b = blockIdx.x / 12;
    const int r = blockIdx.x % 12;
    const int m = r >> 2;
    const int o0 = (r & 3) * 128;
    const float* W = (m == 0) ? wt : (m == 1) ? wp : wg;
    const int tid = threadIdx.x;
    __shared__ float ns[16][512];
    #pragma unroll
    for (int it = 0; it < 32; ++it) {
        int e = it * 256 + tid;
        ns[e >> 9][e & 511] = nodes[(size_t)b * 8192 + e];
    }
    __syncthreads();
    const int o = o0 + (tid & 127);
    const int jg = tid >> 7;
    float acc[8];
    #pragma unroll
    for (int jj = 0; jj < 8; ++jj) acc[jj] = 0.f;
    for (int k4 = 0; k4 < 128; ++k4) {
        float w0 = W[(size_t)(4 * k4 + 0) * 512 + o];
        float w1 = W[(size_t)(4 * k4 + 1) * 512 + o];
        float w2 = W[(size_t)(4 * k4 + 2) * 512 + o];
        float w3 = W[(size_t)(4 * k4 + 3) * 512 + o];
        #pragma unroll
        for (int jj = 0; jj < 8; ++jj) {
            float4 nv = *(const float4*)&ns[jg * 8 + jj][4 * k4];
            acc[jj] += nv.x * w0 + nv.y * w1 + nv.z * w2 + nv.w * w3;
        }
    }
    #pragma unroll
    for (int jj = 0; jj < 8; ++jj)
        qpg[(size_t)((m * 4 + b) * 16 + jg * 8 + jj) * 512 + o] = acc[jj];
}

// ---- 12) STIAU attention + aggregate + cat ---------------------------------
// grid 4, block 256
__global__ __launch_bounds__(256) void k_stiau(const float* __restrict__ nodes, const float* __restrict__ qpg,
                                               const float* __restrict__ NB, float* __restrict__ cat)
{
    const int b = blockIdx.x;
    const int tid = threadIdx.x;
    __shared__ float q_s[16][516];
    __shared__ float p_s[16][516];
    __shared__ float att[16][17];
    #pragma unroll
    for (int it = 0; it < 32; ++it) {
        int e = it * 256 + tid;
        int j = e >> 9, k = e & 511;
        q_s[j][k] = qpg[(size_t)(0 * 4 + b) * 8192 + e];
        p_s[j][k] = qpg[(size_t)(1 * 4 + b) * 8192 + e];
    }
    __syncthreads();
    const int j = tid >> 4, mm = tid & 15;
    float acc = 0.f;
    #pragma unroll
    for (int k4 = 0; k4 < 128; ++k4) {
        float4 qv = *(const float4*)&q_s[j][4 * k4];
        float4 pv = *(const float4*)&p_s[mm][4 * k4];
        acc += qv.x * pv.x + qv.y * pv.y + qv.z * pv.z + qv.w * pv.w;
    }
    acc *= 0.04419417382415922f;   // 1/sqrt(512)
    float mx = acc;
    #pragma unroll
    for (int off = 1; off < 16; off <<= 1) mx = fmaxf(mx, __shfl_xor(mx, off, 64));
    float ev = __expf(acc - mx);
    float sm = ev;
    #pragma unroll
    for (int off = 1; off < 16; off <<= 1) sm += __shfl_xor(sm, off, 64);
    att[j][mm] = ev / sm;
    __syncthreads();
    #pragma unroll
    for (int it = 0; it < 32; ++it) {        // load gg into q_s
        int e = it * 256 + tid;
        q_s[e >> 9][e & 511] = qpg[(size_t)(2 * 4 + b) * 8192 + e];
    }
    __syncthreads();
    #pragma unroll
    for (int it = 0; it < 32; ++it) {        // nodes2 into p_s
        int e = it * 256 + tid;
        int jj = e >> 9, o = e & 511;
        float v = nodes[(size_t)b * 8192 + e];
        #pragma unroll
        for (int m2 = 0; m2 < 16; ++m2) v += att[jj][m2] * q_s[m2][o];
        p_s[jj][o] = v;
    }
    __syncthreads();
    #pragma unroll
    for (int it = 0; it < 16; ++it) {
        int e = it * 256 + tid;   // 0..4095
        int t = e >> 10, cc = e & 1023;
        float val;
        if (cc < 512)
            val = 0.25f * (p_s[t * 4 + 0][cc] + p_s[t * 4 + 1][cc] + p_s[t * 4 + 2][cc] + p_s[t * 4 + 3][cc]);
        else
            val = NB[(size_t)(64 + b) * 512 + (cc - 512)];
        cat[(size_t)(b * 4 + t) * 1024 + cc] = val;
    }
}

// ---- 13) out0[b,o,t] = cat[b,t,:] . w2_w[o,:]  (bias cancels in BN) --------
// grid 64, block 256
__global__ __launch_bounds__(256) void k_w2(const float* __restrict__ cat, const float* __restrict__ w2w,
                                            float* __restrict__ out0)
{
    int flat = blockIdx.x * 256 + threadIdx.x;  // 16384 = b*4096 + o*4 + t
    int b = flat >> 12, o = (flat >> 2) & 1023, t = flat & 3;
    const float4* c4 = (const float4*)(cat + (size_t)(b * 4 + t) * 1024);
    const float4* w4 = (const float4*)(w2w + (size_t)o * 1024);
    float acc = 0.f;
    for (int k = 0; k < 256; ++k) {
        float4 cv = c4[k], wv = w4[k];
        acc += cv.x * wv.x + cv.y * wv.y + cv.z * wv.z + cv.w * wv.w;
    }
    out0[flat] = acc;
}

// ---- 14) BN over (b,t)=16 per channel; z_out = bn(out0) + z ----------------
// grid 1024 (o), block 256
__global__ __launch_bounds__(256) void k_bn2out(const float* __restrict__ out0, const float* __restrict__ g,
                                                const float* __restrict__ beta, const float* __restrict__ z,
                                                float* __restrict__ zout)
{
    const int o = blockIdx.x;
    const int tid = threadIdx.x;
    __shared__ float bnv[16];
    if (tid == 0) {
        float s = 0.f, q = 0.f, vals[16];
        #pragma unroll
        for (int i = 0; i < 16; ++i) {
            int b = i >> 2, t = i & 3;
            float v = out0[(size_t)(b * 1024 + o) * 4 + t];
            vals[i] = v; s += v; q += v * v;
        }
        float m = s * (1.f / 16.f);
        float var = q * (1.f / 16.f) - m * m;
        float rs = rsqrtf(var + EPSBN) * g[o];
        float bb = beta[o] - m * rs;
        #pragma unroll
        for (int i = 0; i < 16; ++i) bnv[i] = vals[i] * rs + bb;
    }
    __syncthreads();
    #pragma unroll
    for (int it = 0; it < 8; ++it) {
        int e = it * 256 + tid;     // bt*128 + p
        int bt = e >> 7, p = e & 127;
        int b = bt >> 2, t = bt & 3;
        size_t idx = (size_t)(b * 1024 + o) * 512 + t * 128 + p;
        zout[idx] = z[idx] + bnv[bt];
    }
}

extern "C" void kernel_launch(void* const* d_in, const int* in_sizes, int n_in,
                              void* d_out, int out_size, void* d_ws, size_t ws_size,
                              hipStream_t stream)
{
    const float* x      = (const float*)d_in[0];
    const float* sa_w   = (const float*)d_in[1];
    // d_in[2] sa_b: cancels in BN
    const float* sa_g   = (const float*)d_in[3];
    const float* sa_be  = (const float*)d_in[4];
    const float* g_w    = (const float*)d_in[5];
    const float* g_b    = (const float*)d_in[6];
    const float* w1_w   = (const float*)d_in[7];
    // d_in[8] w1_b: cancels in BN
    const float* w1_g   = (const float*)d_in[9];
    const float* w1_be  = (const float*)d_in[10];
    const float* w2_w   = (const float*)d_in[11];
    // d_in[12] w2_b: cancels in BN
    const float* w2_g   = (const float*)d_in[13];
    const float* w2_be  = (const float*)d_in[14];
    const float* wt     = (const float*)d_in[15];
    const float* wp     = (const float*)d_in[16];
    const float* wg     = (const float*)d_in[17];
    const float* wu     = (const float*)d_in[18];
    float* out = (float*)d_out;
    float* ws  = (float*)d_ws;
    if (ws_size < (size_t)WS_FLOATS * sizeof(float)) return;  // fail loudly (d_out stays poisoned)

    float* Y    = ws + OFF_Y;
    float* Y1   = ws + OFF_Y1;
    float* Z    = ws + OFF_Z;
    float* BN1  = ws + OFF_BN1;
    float* APRE = ws + OFF_APRE;
    float* SAST = ws + OFF_SAST;
    float* A    = ws + OFF_A;
    float* NBm  = ws + OFF_NB;
    float* NOD  = ws + OFF_NODES;
    float* QPG  = ws + OFF_QPG;
    float* CAT  = ws + OFF_CAT;
    float* OUT0 = ws + OFF_OUT0;
    float* AW   = ws + OFF_AW;
    float* AOUT = out + 2097152;

    hipLaunchKernelGGL(k_attn_mfma, dim3(256),  dim3(256), 0, stream, x, Y);
    hipLaunchKernelGGL(k_w1,      dim3(256),  dim3(256), 0, stream, Y, w1_w, Y1);
    hipLaunchKernelGGL(k_bnstat1, dim3(1024), dim3(256), 0, stream, Y1, BN1);
    hipLaunchKernelGGL(k_zu,      dim3(4096), dim3(128), 0, stream, Y1, x, BN1, w1_g, w1_be, Z, A);
    hipLaunchKernelGGL(k_sa,      dim3(16),   dim3(256), 0, stream, Z, sa_w, APRE);
    hipLaunchKernelGGL(k_sastat,  dim3(4),    dim3(256), 0, stream, APRE, SAST);
    hipLaunchKernelGGL(k_saapply, dim3(32),   dim3(256), 0, stream, APRE, SAST, sa_g, sa_be, AW, AOUT);
    hipLaunchKernelGGL(k_parts,   dim3(16),   dim3(256), 0, stream, Z, AW, A);
    hipLaunchKernelGGL(k_rd,      dim3(136),  dim3(256), 0, stream, A, g_w, g_b, NBm);
    hipLaunchKernelGGL(k_nodes,   dim3(4),    dim3(256), 0, stream, NBm, wu, NOD);
    hipLaunchKernelGGL(k_qpg,     dim3(48),   dim3(256), 0, stream, NOD, wt, wp, wg, QPG);
    hipLaunchKernelGGL(k_stiau,   dim3(4),    dim3(256), 0, stream, NOD, QPG, NBm, CAT);
    hipLaunchKernelGGL(k_w2,      dim3(64),   dim3(256), 0, stream, CAT, w2_w, OUT0);
    hipLaunchKernelGGL(k_bn2out,  dim3(1024), dim3(256), 0, stream, OUT0, w2_g, w2_be, Z, out);
}

// Round 3
// 294.625 us; speedup vs baseline: 3.3691x; 1.5345x over previous
//
#include <hip/hip_runtime.h>
#include <math.h>

#define EPSBN 1e-5f

typedef __attribute__((ext_vector_type(4))) float f32x4;
typedef __attribute__((ext_vector_type(8))) short short8v;
typedef __attribute__((ext_vector_type(4))) short short4v;

__device__ __forceinline__ short f2bf(float f) {
    unsigned u = __float_as_uint(f);
    u = (u + 0x7FFFu + ((u >> 16) & 1u)) >> 16;
    return (short)u;
}

__device__ __forceinline__ void gload16(const void* gp, void* lp) {
    __builtin_amdgcn_global_load_lds(
        (const __attribute__((address_space(1))) unsigned int*)gp,
        (__attribute__((address_space(3))) unsigned int*)lp, 16, 0, 0);
}

// ---- workspace layout (float offsets) --------------------------------------
#define OFF_Y     0          // [0,1048576): Ybf (bf16 perm) ; [1048576,2097152): xbf (bf16 perm)
                             // after k_w1: reused as SAPART (32768 floats)
#define OFF_Y1    2097152    // y1 = w1 conv output, f32 (2097152)
#define OFF_Z     4194304    // first: wbf (bf16, 524288 float-slots); then z f32 (2097152)
#define OFF_BN1   6291456    // mean[1024], var[1024]
#define OFF_APRE  6293504    // sa pre-BN (8192)
#define OFF_SAST  6301696    // mean[4], var[4]
#define OFF_A     6301704    // A matrix 68x1024
#define OFF_NB    6371336    // reduced 68x512
#define OFF_NODES 6406152    // nodes 4x16x512
#define OFF_QPG   6438920    // qt,pp,gg : 3x4x16x512
#define OFF_CAT   6537224    // cat 4x4x1024
#define OFF_OUT0  6553608    // out0 4x1024x4
#define OFF_AW    6569992    // sigmoid a (8192)
#define WS_FLOATS 6578184

// ---- 0) prep: x -> xbf (permuted subtile layout), w1_w -> wbf ---------------
// xbf layout (shorts): b*524288 + tile*8192 + (p>>4)*1024 + (row&63)*16 + (p&15)
__global__ __launch_bounds__(256) void k_prep(const float* __restrict__ x, const float* __restrict__ w1w,
                                              short* __restrict__ xbf, short* __restrict__ wbf)
{
    int e = blockIdx.x * 256 + threadIdx.x;
    if (e < 2097152) {
        float v = x[e];
        int b = e >> 19, rem = e & 524287;
        int row = rem >> 7, p = rem & 127;
        xbf[b * 524288 + (row >> 6) * 8192 + (p >> 4) * 1024 + (row & 63) * 16 + (p & 15)] = f2bf(v);
    } else {
        int e2 = e - 2097152;
        wbf[e2] = f2bf(w1w[e2]);
    }
}

// ---- 1) non-local attention: bf16 MFMA flash, in-block KV split -------------
// grid 256, block 512 = 8 waves: waves 0-3 (half 0) do KV tiles 0..31,
// waves 4-7 (half 1) do tiles 32..63, same 64 Q rows; in-LDS merge at end.
// Staging via global_load_lds from pre-permuted xbf (no VALU, no reg staging).
// Output written directly as bf16 in k_w1's staging layout.
__global__ __launch_bounds__(512, 2) void k_attn_mfma(const short* __restrict__ xbf,
                                                      short* __restrict__ ybf)
{
    __shared__ short KsBuf[2][2][8192];   // [half][buf][8 sub][64 r][16 c]  64 KB
    __shared__ short Pl[8][16 * 72];      // 18 KB
    __shared__ float mlS[4][16][2];

    const int tid  = threadIdx.x;
    const int lane = tid & 63;
    const int wid  = tid >> 6;     // 0..7
    const int half = wid >> 2;
    const int wq   = wid & 3;
    const int g    = lane >> 4;
    const int c15  = lane & 15;

    // XCD-aware decode: 2 XCDs per batch -> each XCD's L2 holds one batch's 1MB xbf
    const int bswz = blockIdx.x;
    const int xcd  = bswz & 7;
    const int bb   = xcd >> 1;
    const int rb   = ((bswz >> 3) << 1) | (xcd & 1);

    const short* xb = xbf + (size_t)bb * 524288;

    // Q fragments: lane holds Q[qrow0+c15][8g+j+32kc] from permuted xbf
    const int qrow0 = rb * 64 + wq * 16;
    short8v qf[4];
    {
        const short* qp = xb + rb * 8192 + (g >> 1) * 1024 + (wq * 16 + c15) * 16 + (g & 1) * 8;
        #pragma unroll
        for (int kc = 0; kc < 4; ++kc)
            qf[kc] = *(const short8v*)(qp + kc * 2048);
    }

    f32x4 yacc[8];
    const f32x4 z4 = {0.f, 0.f, 0.f, 0.f};
    #pragma unroll
    for (int dt = 0; dt < 8; ++dt) yacc[dt] = z4;
    float mrun[4] = {-1e30f, -1e30f, -1e30f, -1e30f};
    float lrun[4] = {0.f, 0.f, 0.f, 0.f};

    const int qkb = (g >> 1) * 1024 + c15 * 16 + (g & 1) * 8;
    const unsigned trL = (unsigned)((8 * g + (c15 >> 2)) * 32 + (c15 & 3) * 8);

    const int t0 = half * 32;
    // prologue: stage first tile of this half into buf 0
    {
        const short* src = xb + (size_t)t0 * 8192;
        #pragma unroll
        for (int i = 0; i < 4; ++i) {
            int off = wq * 2048 + i * 512;
            gload16((const char*)(src + off) + lane * 16, &KsBuf[half][0][off]);
        }
    }
    __syncthreads();

    int cur = 0;
    for (int tn = 0; tn < 32; ++tn) {
        // prefetch next tile (DMA into other buffer, drained by barrier at loop end)
        if (tn < 31) {
            const short* src = xb + (size_t)(t0 + tn + 1) * 8192;
            #pragma unroll
            for (int i = 0; i < 4; ++i) {
                int off = wq * 2048 + i * 512;
                gload16((const char*)(src + off) + lane * 16, &KsBuf[half][cur ^ 1][off]);
            }
        }

        const short* kb = &KsBuf[half][cur][0];

        // ---- QK^T: S tile 16x64 per wave ----
        f32x4 sacc[4];
        #pragma unroll
        for (int nt = 0; nt < 4; ++nt) sacc[nt] = z4;
        #pragma unroll
        for (int kc = 0; kc < 4; ++kc) {
            #pragma unroll
            for (int nt = 0; nt < 4; ++nt) {
                short8v bf = *(const short8v*)&kb[qkb + kc * 2048 + nt * 256];
                sacc[nt] = __builtin_amdgcn_mfma_f32_16x16x32_bf16(qf[kc], bf, sacc[nt], 0, 0, 0);
            }
        }

        // ---- online softmax ----
        float tm[4]; int upd = 0;
        #pragma unroll
        for (int rg = 0; rg < 4; ++rg) {
            float v = fmaxf(fmaxf(sacc[0][rg], sacc[1][rg]), fmaxf(sacc[2][rg], sacc[3][rg]));
            v = fmaxf(v, __shfl_xor(v, 1, 64));
            v = fmaxf(v, __shfl_xor(v, 2, 64));
            v = fmaxf(v, __shfl_xor(v, 4, 64));
            v = fmaxf(v, __shfl_xor(v, 8, 64));
            tm[rg] = v;
            upd |= (v > mrun[rg]) ? 1 : 0;
        }
        if (__any(upd)) {
            #pragma unroll
            for (int rg = 0; rg < 4; ++rg) {
                float mn = fmaxf(mrun[rg], tm[rg]);
                float al = __expf(mrun[rg] - mn);
                mrun[rg] = mn;
                lrun[rg] *= al;
                #pragma unroll
                for (int dt = 0; dt < 8; ++dt) yacc[dt][rg] *= al;
            }
        }
        #pragma unroll
        for (int rg = 0; rg < 4; ++rg) {
            float p0 = __expf(sacc[0][rg] - mrun[rg]);
            float p1 = __expf(sacc[1][rg] - mrun[rg]);
            float p2 = __expf(sacc[2][rg] - mrun[rg]);
            float p3 = __expf(sacc[3][rg] - mrun[rg]);
            short* pw = &Pl[wid][(4 * g + rg) * 72 + c15];
            pw[0]  = f2bf(p0);
            pw[16] = f2bf(p1);
            pw[32] = f2bf(p2);
            pw[48] = f2bf(p3);
            float ts = p0 + p1 + p2 + p3;
            ts += __shfl_xor(ts, 1, 64);
            ts += __shfl_xor(ts, 2, 64);
            ts += __shfl_xor(ts, 4, 64);
            ts += __shfl_xor(ts, 8, 64);
            lrun[rg] += ts;
        }

        // ---- PV: Y += P(16x64) * V(64x128) via tr-read ----
        {
            unsigned kbase = (unsigned)(size_t)kb;
            unsigned trbase = kbase + trL;
            #pragma unroll
            for (int kcp = 0; kcp < 2; ++kcp) {
                short8v pa = *(const short8v*)&Pl[wid][c15 * 72 + kcp * 32 + 8 * g];
                unsigned long long lo[8], hi[8];
                #pragma unroll
                for (int dt = 0; dt < 8; ++dt) {
                    unsigned a = trbase + (unsigned)(kcp * 1024 + dt * 2048);
                    asm volatile("ds_read_b64_tr_b16 %0, %1" : "=v"(lo[dt]) : "v"(a));
                    asm volatile("ds_read_b64_tr_b16 %0, %1 offset:128" : "=v"(hi[dt]) : "v"(a));
                }
                asm volatile("s_waitcnt lgkmcnt(0)" ::: "memory");
                __builtin_amdgcn_sched_barrier(0);
                #pragma unroll
                for (int dt = 0; dt < 8; ++dt) {
                    union { unsigned long long u[2]; short8v s; } fr;
                    fr.u[0] = lo[dt]; fr.u[1] = hi[dt];
                    yacc[dt] = __builtin_amdgcn_mfma_f32_16x16x32_bf16(pa, fr.s, yacc[dt], 0, 0, 0);
                }
            }
        }

        __syncthreads();   // drains DMA (compiler emits vmcnt(0)) + protects buffer flip
        cur ^= 1;
    }

    // ---- merge halves in LDS (KsBuf is free now) ----
    float* ys = (float*)&KsBuf[0][0][0];   // 32 KB area for upper-half yacc
    if (half == 1) {
        #pragma unroll
        for (int rg = 0; rg < 4; ++rg) {
            #pragma unroll
            for (int dt = 0; dt < 8; ++dt)
                ys[wq * 2048 + (4 * g + rg) * 128 + 16 * dt + c15] = yacc[dt][rg];
            if (c15 == 0) {
                mlS[wq][4 * g + rg][0] = mrun[rg];
                mlS[wq][4 * g + rg][1] = lrun[rg];
            }
        }
    }
    __syncthreads();
    if (half == 0) {
        #pragma unroll
        for (int rg = 0; rg < 4; ++rg) {
            float m1 = mlS[wq][4 * g + rg][0];
            float l1 = mlS[wq][4 * g + rg][1];
            float M  = fmaxf(mrun[rg], m1);
            float w0 = __expf(mrun[rg] - M);
            float w1 = __expf(m1 - M);
            float inv = 1.f / (lrun[rg] * w0 + l1 * w1);
            int row = qrow0 + 4 * g + rg;         // ct index
            int cch = row >> 2, t = row & 3;
            int ctile = cch >> 6, crow = cch & 63;
            #pragma unroll
            for (int dt = 0; dt < 8; ++dt) {
                float v = (yacc[dt][rg] * w0 + ys[wq * 2048 + (4 * g + rg) * 128 + 16 * dt + c15] * w1) * inv;
                int pos = t * 128 + dt * 16 + c15;
                // Ybf perm layout for k_w1: ((b*16+ctile)*8 + pos>>6)*4096 + ((pos>>4)&3)*1024 + crow*16 + (pos&15)
                ybf[(size_t)((bb * 16 + ctile) * 8 + (pos >> 6)) * 4096 +
                    ((pos >> 4) & 3) * 1024 + crow * 16 + (pos & 15)] = f2bf(v);
            }
        }
    }
}

// ---- 2) y1 = W1 @ Y via bf16 MFMA ------------------------------------------
// grid 512 = ot(16) x pt(8) x b(4); block 256 = 4 waves x 16 o-rows; 64 o x 64 pos tile.
// B-tile staged from Ybf (already permuted) via global_load_lds; B-frags via tr-read.
__global__ __launch_bounds__(256, 2) void k_w1_mfma(const short* __restrict__ ybf,
                                                    const short* __restrict__ wbf,
                                                    float* __restrict__ y1)
{
    __shared__ short Kw[2][4096];   // [buf][4 sub][64 c][16 pos] 16 KB
    const int tid = threadIdx.x, lane = tid & 63, wid = tid >> 6;
    const int g = lane >> 4, c15 = lane & 15;
    const int b = blockIdx.x & 3, pt = (blockIdx.x >> 2) & 7, ot = blockIdx.x >> 5;

    f32x4 acc[4];
    const f32x4 z4 = {0.f, 0.f, 0.f, 0.f};
    #pragma unroll
    for (int dt = 0; dt < 4; ++dt) acc[dt] = z4;

    const unsigned trL = (unsigned)((8 * g + (c15 >> 2)) * 32 + (c15 & 3) * 8);
    const short* wrow = wbf + (size_t)(ot * 64 + wid * 16 + c15) * 1024;

    // prologue: stage c-chunk 0
    {
        const short* src = ybf + (size_t)((b * 16 + 0) * 8 + pt) * 4096;
        #pragma unroll
        for (int i = 0; i < 2; ++i) {
            int off = wid * 1024 + i * 512;
            gload16((const char*)(src + off) + lane * 16, &Kw[0][off]);
        }
    }
    __syncthreads();

    int cur = 0;
    for (int cc = 0; cc < 16; ++cc) {
        if (cc < 15) {
            const short* src = ybf + (size_t)((b * 16 + cc + 1) * 8 + pt) * 4096;
            #pragma unroll
            for (int i = 0; i < 2; ++i) {
                int off = wid * 1024 + i * 512;
                gload16((const char*)(src + off) + lane * 16, &Kw[cur ^ 1][off]);
            }
        }
        short8v af[2];
        af[0] = *(const short8v*)(wrow + cc * 64 + 8 * g);
        af[1] = *(const short8v*)(wrow + cc * 64 + 32 + 8 * g);

        unsigned kbase = (unsigned)(size_t)&Kw[cur][0];
        unsigned trbase = kbase + trL;
        #pragma unroll
        for (int kcp = 0; kcp < 2; ++kcp) {
            unsigned long long lo[4], hi[4];
            #pragma unroll
            for (int dt = 0; dt < 4; ++dt) {
                unsigned a = trbase + (unsigned)(kcp * 1024 + dt * 2048);
                asm volatile("ds_read_b64_tr_b16 %0, %1" : "=v"(lo[dt]) : "v"(a));
                asm volatile("ds_read_b64_tr_b16 %0, %1 offset:128" : "=v"(hi[dt]) : "v"(a));
            }
            asm volatile("s_waitcnt lgkmcnt(0)" ::: "memory");
            __builtin_amdgcn_sched_barrier(0);
            #pragma unroll
            for (int dt = 0; dt < 4; ++dt) {
                union { unsigned long long u[2]; short8v s; } fr;
                fr.u[0] = lo[dt]; fr.u[1] = hi[dt];
                acc[dt] = __builtin_amdgcn_mfma_f32_16x16x32_bf16(af[kcp], fr.s, acc[dt], 0, 0, 0);
            }
        }
        __syncthreads();
        cur ^= 1;
    }

    const int o0 = ot * 64 + wid * 16 + 4 * g;
    #pragma unroll
    for (int dt = 0; dt < 4; ++dt)
        #pragma unroll
        for (int rg = 0; rg < 4; ++rg)
            y1[(size_t)(b * 1024 + o0 + rg) * 512 + pt * 64 + 16 * dt + c15] = acc[dt][rg];
}

// ---- 3) BN stats over (b,t,h,w)=2048 per channel ---------------------------
__global__ __launch_bounds__(256) void k_bnstat1(const float* __restrict__ y1, float* __restrict__ stat)
{
    const int o = blockIdx.x;
    const int tid = threadIdx.x;
    float s = 0.f, q = 0.f;
    #pragma unroll
    for (int it = 0; it < 8; ++it) {
        int e = it * 256 + tid;
        int b = e >> 9, j = e & 511;
        float v = y1[(size_t)(b * 1024 + o) * 512 + j];
        s += v; q += v * v;
    }
    #pragma unroll
    for (int off = 32; off > 0; off >>= 1) { s += __shfl_down(s, off, 64); q += __shfl_down(q, off, 64); }
    __shared__ float ss[4], qq[4];
    if ((tid & 63) == 0) { ss[tid >> 6] = s; qq[tid >> 6] = q; }
    __syncthreads();
    if (tid == 0) {
        float S = ss[0] + ss[1] + ss[2] + ss[3];
        float Q = qq[0] + qq[1] + qq[2] + qq[3];
        float m = S * (1.f / 2048.f);
        stat[o] = m;
        stat[1024 + o] = Q * (1.f / 2048.f) - m * m;
    }
}

// ---- 4) z = bn(y1)+x ; u[b,c] = mean_thw(z) into A rows 64..67 -------------
__global__ __launch_bounds__(128) void k_zu(const float* __restrict__ y1, const float* __restrict__ x,
                                            const float* __restrict__ stat, const float* __restrict__ g,
                                            const float* __restrict__ beta, float* __restrict__ z,
                                            float* __restrict__ A)
{
    const int blk = blockIdx.x;
    const int b = blk >> 10, o = blk & 1023;
    const int tid = threadIdx.x;
    float rs = rsqrtf(stat[1024 + o] + EPSBN) * g[o];
    float bt = beta[o] - stat[o] * rs;
    size_t base = (size_t)blk * 512;
    float sum = 0.f;
    #pragma unroll
    for (int it = 0; it < 4; ++it) {
        int j = it * 128 + tid;
        float v = y1[base + j] * rs + bt + x[base + j];
        z[base + j] = v;
        sum += v;
    }
    #pragma unroll
    for (int off = 32; off > 0; off >>= 1) sum += __shfl_down(sum, off, 64);
    __shared__ float red[2];
    if ((tid & 63) == 0) red[tid >> 6] = sum;
    __syncthreads();
    if (tid == 0) A[(size_t)(64 + b) * 1024 + o] = (red[0] + red[1]) * (1.f / 512.f);
}

// ---- 5) spatial-attn partial: sapart[cq][bt][n][p] = sum_{c in chunk} z*sa_w -
// grid 64 = bt(16) x cq(4), block 256
__global__ __launch_bounds__(256) void k_sap(const float* __restrict__ z, const float* __restrict__ saw,
                                             float* __restrict__ sapart)
{
    const int bt = blockIdx.x >> 2, cq = blockIdx.x & 3;
    const int b = bt >> 2, t = bt & 3;
    const int tid = threadIdx.x;
    __shared__ float wsm[4][256];
    __shared__ float part[2][4][128];
    #pragma unroll
    for (int it = 0; it < 4; ++it) {
        int e = it * 256 + tid;
        wsm[e >> 8][e & 255] = saw[(e >> 8) * 1024 + cq * 256 + (e & 255)];
    }
    __syncthreads();
    const int p = tid & 127, half = tid >> 7;
    float a0 = 0, a1 = 0, a2 = 0, a3 = 0;
    for (int ci = 0; ci < 128; ++ci) {
        int cl = half * 128 + ci;
        float zv = z[(size_t)(b * 1024 + cq * 256 + cl) * 512 + t * 128 + p];
        a0 += zv * wsm[0][cl]; a1 += zv * wsm[1][cl];
        a2 += zv * wsm[2][cl]; a3 += zv * wsm[3][cl];
    }
    part[half][0][p] = a0; part[half][1][p] = a1;
    part[half][2][p] = a2; part[half][3][p] = a3;
    __syncthreads();
    #pragma unroll
    for (int it = 0; it < 2; ++it) {
        int e = it * 256 + tid;
        int n = e >> 7, pp = e & 127;
        sapart[(size_t)((cq * 16 + bt) * 4 + n) * 128 + pp] = part[0][n][pp] + part[1][n][pp];
    }
}

// ---- 6) reduce partials -> apre + BN stats per n ----------------------------
__global__ __launch_bounds__(256) void k_sastat(const float* __restrict__ sapart, float* __restrict__ apre,
                                                float* __restrict__ stat)
{
    const int n = blockIdx.x;
    const int tid = threadIdx.x;
    float s = 0.f, q = 0.f;
    #pragma unroll
    for (int it = 0; it < 8; ++it) {
        int e = it * 256 + tid;           // bt*128 + p
        int bt = e >> 7, p = e & 127;
        float v = 0.f;
        #pragma unroll
        for (int cq = 0; cq < 4; ++cq)
            v += sapart[(size_t)((cq * 16 + bt) * 4 + n) * 128 + p];
        int b = bt >> 2, t = bt & 3;
        apre[(size_t)((b * 4 + n) * 4 + t) * 128 + p] = v;
        s += v; q += v * v;
    }
    #pragma unroll
    for (int off = 32; off > 0; off >>= 1) { s += __shfl_down(s, off, 64); q += __shfl_down(q, off, 64); }
    __shared__ float ss[4], qq[4];
    if ((tid & 63) == 0) { ss[tid >> 6] = s; qq[tid >> 6] = q; }
    __syncthreads();
    if (tid == 0) {
        float S = ss[0] + ss[1] + ss[2] + ss[3];
        float Q = qq[0] + qq[1] + qq[2] + qq[3];
        float m = S * (1.f / 2048.f);
        stat[n] = m;
        stat[4 + n] = Q * (1.f / 2048.f) - m * m;
    }
}

// ---- 7) a = sigmoid(bn(apre)); write ws copy + a_out -----------------------
__global__ __launch_bounds__(256) void k_saapply(const float* __restrict__ apre, const float* __restrict__ stat,
                                                 const float* __restrict__ sag, const float* __restrict__ sabeta,
                                                 float* __restrict__ aw, float* __restrict__ aout)
{
    int e = blockIdx.x * 256 + threadIdx.x;   // 8192
    int p = e & 127, t = (e >> 7) & 3, n = (e >> 9) & 3, b = e >> 11;
    float val = (apre[e] - stat[n]) * rsqrtf(stat[4 + n] + EPSBN) * sag[n] + sabeta[n];
    float sig = 1.f / (1.f + __expf(-val));
    aw[e] = sig;
    aout[(size_t)((b * 4 + t) * 4 + n) * 128 + p] = sig;
}

// ---- 8) parts[b,t,n,c] = sum_p a[n,p] z[c,p] into A rows 0..63 -------------
// grid 64 = bt(16) x cq(4), block 256
__global__ __launch_bounds__(256) void k_parts(const float* __restrict__ z, const float* __restrict__ aw,
                                               float* __restrict__ A)
{
    const int bt = blockIdx.x >> 2, cq = blockIdx.x & 3;
    const int b = bt >> 2, t = bt & 3;
    const int tid = threadIdx.x;
    __shared__ float As[4][132];
    __shared__ float Zs[64][132];
    #pragma unroll
    for (int it = 0; it < 2; ++it) {
        int e = it * 256 + tid;
        int n = e >> 7, p = e & 127;
        As[n][p] = aw[(size_t)((b * 4 + n) * 4 + t) * 128 + p];
    }
    const int cl = tid >> 2, n = tid & 3;
    for (int c0 = cq * 256; c0 < cq * 256 + 256; c0 += 64) {
        #pragma unroll
        for (int it = 0; it < 8; ++it) {
            int e = (it * 256 + tid) * 4;
            int r = e >> 7, cc = e & 127;
            *(float4*)&Zs[r][cc] = *(const float4*)(z + (size_t)(b * 1024 + c0 + r) * 512 + t * 128 + cc);
        }
        __syncthreads();
        float acc = 0.f;
        #pragma unroll
        for (int k4 = 0; k4 < 32; ++k4) {
            float4 zv = *(const float4*)&Zs[cl][4 * k4];
            float4 av = *(const float4*)&As[n][4 * k4];
            acc += zv.x * av.x + zv.y * av.y + zv.z * av.z + zv.w * av.w;
        }
        A[(size_t)(b * 16 + t * 4 + n) * 1024 + c0 + cl] = acc;
        __syncthreads();
    }
}

// ---- 9) reduce_dimension: NB[68][512] = A[68][1024] @ g_w^T + g_b ----------
__global__ __launch_bounds__(256) void k_rd(const float* __restrict__ A, const float* __restrict__ gw,
                                            const float* __restrict__ gb, float* __restrict__ NB)
{
    int flat = blockIdx.x * 256 + threadIdx.x;   // 0..34815
    int row = flat >> 9, o = flat & 511;
    const float4* a4 = (const float4*)(A + (size_t)row * 1024);
    const float4* w4 = (const float4*)(gw + (size_t)o * 1024);
    float acc = 0.f;
    for (int k = 0; k < 256; ++k) {
        float4 av = a4[k], wv = w4[k];
        acc += av.x * wv.x + av.y * wv.y + av.z * wv.z + av.w * wv.w;
    }
    NB[flat] = acc + gb[o];
}

// ---- 10) nodes[b,j,o] = parts_r + (u_r @ wu)[o] ----------------------------
__global__ __launch_bounds__(256) void k_nodes(const float* __restrict__ NB, const float* __restrict__ wu,
                                               float* __restrict__ nodes)
{
    const int b = blockIdx.x;
    const int tid = threadIdx.x;
    __shared__ float us[512];
    __shared__ float uwu[512];
    us[tid] = NB[(size_t)(64 + b) * 512 + tid];
    us[tid + 256] = NB[(size_t)(64 + b) * 512 + tid + 256];
    __syncthreads();
    #pragma unroll
    for (int hh = 0; hh < 2; ++hh) {
        int o = hh * 256 + tid;
        float acc = 0.f;
        for (int k = 0; k < 512; ++k) acc += us[k] * wu[(size_t)k * 512 + o];
        uwu[o] = acc;
    }
    __syncthreads();
    #pragma unroll
    for (int it = 0; it < 32; ++it) {
        int e = it * 256 + tid;
        nodes[(size_t)b * 8192 + e] = NB[(size_t)b * 8192 + e] + uwu[e & 511];
    }
}

// ---- 11) qt/pp/gg = nodes @ {wt,wp,wg} -------------------------------------
__global__ __launch_bounds__(256) void k_qpg(const float* __restrict__ nodes, const float* __restrict__ wt,
                                             const float* __restrict__ wp, const float* __restrict__ wg,
                                             float* __restrict__ qpg)
{
    const int b = blockIdx.x / 12;
    const int r = blockIdx.x % 12;
    const int m = r >> 2;
    const int o0 = (r & 3) * 128;
    const float* W = (m == 0) ? wt : (m == 1) ? wp : wg;
    const int tid = threadIdx.x;
    __shared__ float ns[16][512];
    #pragma unroll
    for (int it = 0; it < 32; ++it) {
        int e = it * 256 + tid;
        ns[e >> 9][e & 511] = nodes[(size_t)b * 8192 + e];
    }
    __syncthreads();
    const int o = o0 + (tid & 127);
    const int jg = tid >> 7;
    float acc[8];
    #pragma unroll
    for (int jj = 0; jj < 8; ++jj) acc[jj] = 0.f;
    for (int k4 = 0; k4 < 128; ++k4) {
        float w0 = W[(size_t)(4 * k4 + 0) * 512 + o];
        float w1 = W[(size_t)(4 * k4 + 1) * 512 + o];
        float w2 = W[(size_t)(4 * k4 + 2) * 512 + o];
        float w3 = W[(size_t)(4 * k4 + 3) * 512 + o];
        #pragma unroll
        for (int jj = 0; jj < 8; ++jj) {
            float4 nv = *(const float4*)&ns[jg * 8 + jj][4 * k4];
            acc[jj] += nv.x * w0 + nv.y * w1 + nv.z * w2 + nv.w * w3;
        }
    }
    #pragma unroll
    for (int jj = 0; jj < 8; ++jj)
        qpg[(size_t)((m * 4 + b) * 16 + jg * 8 + jj) * 512 + o] = acc[jj];
}

// ---- 12) STIAU attention + aggregate + cat ---------------------------------
__global__ __launch_bounds__(256) void k_stiau(const float* __restrict__ nodes, const float* __restrict__ qpg,
                                               const float* __restrict__ NB, float* __restrict__ cat)
{
    const int b = blockIdx.x;
    const int tid = threadIdx.x;
    __shared__ float q_s[16][516];
    __shared__ float p_s[16][516];
    __shared__ float att[16][17];
    #pragma unroll
    for (int it = 0; it < 32; ++it) {
        int e = it * 256 + tid;
        int j = e >> 9, k = e & 511;
        q_s[j][k] = qpg[(size_t)(0 * 4 + b) * 8192 + e];
        p_s[j][k] = qpg[(size_t)(1 * 4 + b) * 8192 + e];
    }
    __syncthreads();
    const int j = tid >> 4, mm = tid & 15;
    float acc = 0.f;
    #pragma unroll
    for (int k4 = 0; k4 < 128; ++k4) {
        float4 qv = *(const float4*)&q_s[j][4 * k4];
        float4 pv = *(const float4*)&p_s[mm][4 * k4];
        acc += qv.x * pv.x + qv.y * pv.y + qv.z * pv.z + qv.w * pv.w;
    }
    acc *= 0.04419417382415922f;   // 1/sqrt(512)
    float mx = acc;
    #pragma unroll
    for (int off = 1; off < 16; off <<= 1) mx = fmaxf(mx, __shfl_xor(mx, off, 64));
    float ev = __expf(acc - mx);
    float sm = ev;
    #pragma unroll
    for (int off = 1; off < 16; off <<= 1) sm += __shfl_xor(sm, off, 64);
    att[j][mm] = ev / sm;
    __syncthreads();
    #pragma unroll
    for (int it = 0; it < 32; ++it) {
        int e = it * 256 + tid;
        q_s[e >> 9][e & 511] = qpg[(size_t)(2 * 4 + b) * 8192 + e];
    }
    __syncthreads();
    #pragma unroll
    for (int it = 0; it < 32; ++it) {
        int e = it * 256 + tid;
        int jj = e >> 9, o = e & 511;
        float v = nodes[(size_t)b * 8192 + e];
        #pragma unroll
        for (int m2 = 0; m2 < 16; ++m2) v += att[jj][m2] * q_s[m2][o];
        p_s[jj][o] = v;
    }
    __syncthreads();
    #pragma unroll
    for (int it = 0; it < 16; ++it) {
        int e = it * 256 + tid;   // 0..4095
        int t = e >> 10, cc = e & 1023;
        float val;
        if (cc < 512)
            val = 0.25f * (p_s[t * 4 + 0][cc] + p_s[t * 4 + 1][cc] + p_s[t * 4 + 2][cc] + p_s[t * 4 + 3][cc]);
        else
            val = NB[(size_t)(64 + b) * 512 + (cc - 512)];
        cat[(size_t)(b * 4 + t) * 1024 + cc] = val;
    }
}

// ---- 13) out0[b,o,t] = cat[b,t,:] . w2_w[o,:] ------------------------------
__global__ __launch_bounds__(256) void k_w2(const float* __restrict__ cat, const float* __restrict__ w2w,
                                            float* __restrict__ out0)
{
    int flat = blockIdx.x * 256 + threadIdx.x;  // 16384 = b*4096 + o*4 + t
    int b = flat >> 12, o = (flat >> 2) & 1023, t = flat & 3;
    const float4* c4 = (const float4*)(cat + (size_t)(b * 4 + t) * 1024);
    const float4* w4 = (const float4*)(w2w + (size_t)o * 1024);
    float acc = 0.f;
    for (int k = 0; k < 256; ++k) {
        float4 cv = c4[k], wv = w4[k];
        acc += cv.x * wv.x + cv.y * wv.y + cv.z * wv.z + cv.w * wv.w;
    }
    out0[flat] = acc;
}

// ---- 14) BN over (b,t)=16 per channel; z_out = bn(out0) + z ----------------
__global__ __launch_bounds__(256) void k_bn2out(const float* __restrict__ out0, const float* __restrict__ g,
                                                const float* __restrict__ beta, const float* __restrict__ z,
                                                float* __restrict__ zout)
{
    const int o = blockIdx.x;
    const int tid = threadIdx.x;
    __shared__ float bnv[16];
    if (tid == 0) {
        float s = 0.f, q = 0.f, vals[16];
        #pragma unroll
        for (int i = 0; i < 16; ++i) {
            int b = i >> 2, t = i & 3;
            float v = out0[(size_t)(b * 1024 + o) * 4 + t];
            vals[i] = v; s += v; q += v * v;
        }
        float m = s * (1.f / 16.f);
        float var = q * (1.f / 16.f) - m * m;
        float rs = rsqrtf(var + EPSBN) * g[o];
        float bb = beta[o] - m * rs;
        #pragma unroll
        for (int i = 0; i < 16; ++i) bnv[i] = vals[i] * rs + bb;
    }
    __syncthreads();
    #pragma unroll
    for (int it = 0; it < 8; ++it) {
        int e = it * 256 + tid;     // bt*128 + p
        int bt = e >> 7, p = e & 127;
        int b = bt >> 2, t = bt & 3;
        size_t idx = (size_t)(b * 1024 + o) * 512 + t * 128 + p;
        zout[idx] = z[idx] + bnv[bt];
    }
}

extern "C" void kernel_launch(void* const* d_in, const int* in_sizes, int n_in,
                              void* d_out, int out_size, void* d_ws, size_t ws_size,
                              hipStream_t stream)
{
    const float* x      = (const float*)d_in[0];
    const float* sa_w   = (const float*)d_in[1];
    // d_in[2] sa_b: cancels in BN
    const float* sa_g   = (const float*)d_in[3];
    const float* sa_be  = (const float*)d_in[4];
    const float* g_w    = (const float*)d_in[5];
    const float* g_b    = (const float*)d_in[6];
    const float* w1_w   = (const float*)d_in[7];
    // d_in[8] w1_b: cancels in BN
    const float* w1_g   = (const float*)d_in[9];
    const float* w1_be  = (const float*)d_in[10];
    const float* w2_w   = (const float*)d_in[11];
    // d_in[12] w2_b: cancels in BN
    const float* w2_g   = (const float*)d_in[13];
    const float* w2_be  = (const float*)d_in[14];
    const float* wt     = (const float*)d_in[15];
    const float* wp     = (const float*)d_in[16];
    const float* wg     = (const float*)d_in[17];
    const float* wu     = (const float*)d_in[18];
    float* out = (float*)d_out;
    float* ws  = (float*)d_ws;
    if (ws_size < (size_t)WS_FLOATS * sizeof(float)) return;  // fail loudly

    short* YBF  = (short*)(ws + OFF_Y);            // bf16 attention output (perm)
    short* XBF  = (short*)(ws + OFF_Y + 1048576);  // bf16 x (perm)
    short* WBF  = (short*)(ws + OFF_Z);            // bf16 w1 (dead after k_w1; z overwrites)
    float* Y1   = ws + OFF_Y1;
    float* Z    = ws + OFF_Z;
    float* BN1  = ws + OFF_BN1;
    float* APRE = ws + OFF_APRE;
    float* SAST = ws + OFF_SAST;
    float* A    = ws + OFF_A;
    float* NBm  = ws + OFF_NB;
    float* NOD  = ws + OFF_NODES;
    float* QPG  = ws + OFF_QPG;
    float* CAT  = ws + OFF_CAT;
    float* OUT0 = ws + OFF_OUT0;
    float* AW   = ws + OFF_AW;
    float* SAPART = ws + OFF_Y;                    // reuses Ybf region (dead after k_w1)
    float* AOUT = out + 2097152;

    hipLaunchKernelGGL(k_prep,      dim3(12288), dim3(256), 0, stream, x, w1_w, XBF, WBF);
    hipLaunchKernelGGL(k_attn_mfma, dim3(256),   dim3(512), 0, stream, XBF, YBF);
    hipLaunchKernelGGL(k_w1_mfma,   dim3(512),   dim3(256), 0, stream, YBF, WBF, Y1);
    hipLaunchKernelGGL(k_bnstat1,   dim3(1024),  dim3(256), 0, stream, Y1, BN1);
    hipLaunchKernelGGL(k_zu,        dim3(4096),  dim3(128), 0, stream, Y1, x, BN1, w1_g, w1_be, Z, A);
    hipLaunchKernelGGL(k_sap,       dim3(64),    dim3(256), 0, stream, Z, sa_w, SAPART);
    hipLaunchKernelGGL(k_sastat,    dim3(4),     dim3(256), 0, stream, SAPART, APRE, SAST);
    hipLaunchKernelGGL(k_saapply,   dim3(32),    dim3(256), 0, stream, APRE, SAST, sa_g, sa_be, AW, AOUT);
    hipLaunchKernelGGL(k_parts,     dim3(64),    dim3(256), 0, stream, Z, AW, A);
    hipLaunchKernelGGL(k_rd,        dim3(136),   dim3(256), 0, stream, A, g_w, g_b, NBm);
    hipLaunchKernelGGL(k_nodes,     dim3(4),     dim3(256), 0, stream, NBm, wu, NOD);
    hipLaunchKernelGGL(k_qpg,       dim3(48),    dim3(256), 0, stream, NOD, wt, wp, wg, QPG);
    hipLaunchKernelGGL(k_stiau,     dim3(4),     dim3(256), 0, stream, NOD, QPG, NBm, CAT);
    hipLaunchKernelGGL(k_w2,        dim3(64),    dim3(256), 0, stream, CAT, w2_w, OUT0);
    hipLaunchKernelGGL(k_bn2out,    dim3(1024),  dim3(256), 0, stream, OUT0, w2_g, w2_be, Z, out);
}

// Round 4
// 261.840 us; speedup vs baseline: 3.7910x; 1.1252x over previous
//
#include <hip/hip_runtime.h>
#include <math.h>

#define EPSBN 1e-5f

typedef __attribute__((ext_vector_type(4))) float f32x4;
typedef __attribute__((ext_vector_type(8))) short short8v;
typedef __attribute__((ext_vector_type(4))) short short4v;

__device__ __forceinline__ short f2bf(float f) {
    unsigned u = __float_as_uint(f);
    u = (u + 0x7FFFu + ((u >> 16) & 1u)) >> 16;
    return (short)u;
}

__device__ __forceinline__ void gload16(const void* gp, void* lp) {
    __builtin_amdgcn_global_load_lds(
        (const __attribute__((address_space(1))) unsigned int*)gp,
        (__attribute__((address_space(3))) unsigned int*)lp, 16, 0, 0);
}

// ---- workspace layout (float offsets) --------------------------------------
#define OFF_Y     0          // [0,1048576): Ybf (bf16 perm) ; [1048576,2097152): xbf (bf16 perm)
                             // after k_w1: reused as SAPART (32768 floats)
#define OFF_Y1    2097152    // y1 = w1 conv output, f32 (2097152)
#define OFF_Z     4194304    // first: wbf (bf16, 1048576 shorts); then z f32 (2097152)
#define OFF_BN1   6291456    // sum[1024], sumsq[1024]  (atomics; memset to 0 each call)
#define OFF_A     6301704    // A matrix 68x1024
#define OFF_NB    6371336    // reduced 68x512
#define OFF_NODES 6406152    // nodes 4x16x512
#define OFF_QPG   6438920    // qt,pp,gg : 3x4x16x512
#define OFF_CAT   6537224    // cat 4x4x1024
#define OFF_OUT0  6553608    // out0 4x1024x4
#define OFF_AW    6569992    // sigmoid a (8192)
#define WS_FLOATS 6578184

// ---- 0) prep: x -> xbf (permuted subtile layout), w1_w -> wbf ---------------
__global__ __launch_bounds__(256) void k_prep(const float* __restrict__ x, const float* __restrict__ w1w,
                                              short* __restrict__ xbf, short* __restrict__ wbf)
{
    int e = blockIdx.x * 256 + threadIdx.x;
    if (e < 2097152) {
        float v = x[e];
        int b = e >> 19, rem = e & 524287;
        int row = rem >> 7, p = rem & 127;
        xbf[b * 524288 + (row >> 6) * 8192 + (p >> 4) * 1024 + (row & 63) * 16 + (p & 15)] = f2bf(v);
    } else {
        int e2 = e - 2097152;
        wbf[e2] = f2bf(w1w[e2]);
    }
}

// ---- 1) non-local attention: bf16 MFMA flash, in-block KV split -------------
// 8 waves: waves 0-3 do KV tiles 0..31, waves 4-7 do 32..63 (rotated so the
// diagonal tile comes first); lazy-max (ballot-guarded) + deferred sum reduce.
__global__ __launch_bounds__(512, 1) void k_attn_mfma(const short* __restrict__ xbf,
                                                      short* __restrict__ ybf)
{
    __shared__ short KsBuf[2][2][8192];   // [half][buf] 64 KB
    __shared__ short Pl[8][16 * 72];      // 18 KB
    __shared__ float mlS[4][16][2];

    const int tid  = threadIdx.x;
    const int lane = tid & 63;
    const int wid  = tid >> 6;
    const int half = wid >> 2;
    const int wq   = wid & 3;
    const int g    = lane >> 4;
    const int c15  = lane & 15;

    const int bswz = blockIdx.x;
    const int xcd  = bswz & 7;
    const int bb   = xcd >> 1;
    const int rb   = ((bswz >> 3) << 1) | (xcd & 1);

    const short* xb = xbf + (size_t)bb * 524288;

    const int qrow0 = rb * 64 + wq * 16;
    short8v qf[4];
    {
        const short* qp = xb + rb * 8192 + (g >> 1) * 1024 + (wq * 16 + c15) * 16 + (g & 1) * 8;
        #pragma unroll
        for (int kc = 0; kc < 4; ++kc)
            qf[kc] = *(const short8v*)(qp + kc * 2048);
    }

    f32x4 yacc[8];
    const f32x4 z4 = {0.f, 0.f, 0.f, 0.f};
    #pragma unroll
    for (int dt = 0; dt < 8; ++dt) yacc[dt] = z4;
    float mrun[4] = {-1e30f, -1e30f, -1e30f, -1e30f};
    float lsum[4] = {0.f, 0.f, 0.f, 0.f};

    const int qkb = (g >> 1) * 1024 + c15 * 16 + (g & 1) * 8;
    const unsigned trL = (unsigned)((8 * g + (c15 >> 2)) * 32 + (c15 & 3) * 8);

    const int t0 = half * 32;
    const int r0 = rb & 31;          // rotation: diagonal tile first (for its half)
    // prologue: stage first tile
    {
        const short* src = xb + (size_t)(t0 + r0) * 8192;
        #pragma unroll
        for (int i = 0; i < 4; ++i) {
            int off = wq * 2048 + i * 512;
            gload16((const char*)(src + off) + lane * 16, &KsBuf[half][0][off]);
        }
    }
    __syncthreads();

    int cur = 0;
    for (int tn = 0; tn < 32; ++tn) {
        if (tn < 31) {
            const short* src = xb + (size_t)(t0 + ((tn + 1 + r0) & 31)) * 8192;
            #pragma unroll
            for (int i = 0; i < 4; ++i) {
                int off = wq * 2048 + i * 512;
                gload16((const char*)(src + off) + lane * 16, &KsBuf[half][cur ^ 1][off]);
            }
        }

        const short* kb = &KsBuf[half][cur][0];

        // ---- QK^T ----
        f32x4 sacc[4];
        #pragma unroll
        for (int nt = 0; nt < 4; ++nt) sacc[nt] = z4;
        #pragma unroll
        for (int kc = 0; kc < 4; ++kc) {
            #pragma unroll
            for (int nt = 0; nt < 4; ++nt) {
                short8v bf = *(const short8v*)&kb[qkb + kc * 2048 + nt * 256];
                sacc[nt] = __builtin_amdgcn_mfma_f32_16x16x32_bf16(qf[kc], bf, sacc[nt], 0, 0, 0);
            }
        }

        // ---- lazy max: only lane-local check in steady state ----
        float lmax[4]; int upd = 0;
        #pragma unroll
        for (int rg = 0; rg < 4; ++rg) {
            lmax[rg] = fmaxf(fmaxf(sacc[0][rg], sacc[1][rg]), fmaxf(sacc[2][rg], sacc[3][rg]));
            upd |= (lmax[rg] > mrun[rg]) ? 1 : 0;
        }
        if (__any(upd)) {   // rare: full reduce + rescale
            #pragma unroll
            for (int rg = 0; rg < 4; ++rg) {
                float v = lmax[rg];
                v = fmaxf(v, __shfl_xor(v, 1, 64));
                v = fmaxf(v, __shfl_xor(v, 2, 64));
                v = fmaxf(v, __shfl_xor(v, 4, 64));
                v = fmaxf(v, __shfl_xor(v, 8, 64));
                float mn = fmaxf(mrun[rg], v);
                float al = __expf(mrun[rg] - mn);
                mrun[rg] = mn;
                lsum[rg] *= al;
                #pragma unroll
                for (int dt = 0; dt < 8; ++dt) yacc[dt][rg] *= al;
            }
        }
        #pragma unroll
        for (int rg = 0; rg < 4; ++rg) {
            float p0 = __expf(sacc[0][rg] - mrun[rg]);
            float p1 = __expf(sacc[1][rg] - mrun[rg]);
            float p2 = __expf(sacc[2][rg] - mrun[rg]);
            float p3 = __expf(sacc[3][rg] - mrun[rg]);
            short* pw = &Pl[wid][(4 * g + rg) * 72 + c15];
            pw[0]  = f2bf(p0);
            pw[16] = f2bf(p1);
            pw[32] = f2bf(p2);
            pw[48] = f2bf(p3);
            lsum[rg] += p0 + p1 + p2 + p3;   // per-lane partial; reduced once at end
        }

        // ---- PV via tr-read ----
        {
            unsigned kbase = (unsigned)(size_t)kb;
            unsigned trbase = kbase + trL;
            #pragma unroll
            for (int kcp = 0; kcp < 2; ++kcp) {
                short8v pa = *(const short8v*)&Pl[wid][c15 * 72 + kcp * 32 + 8 * g];
                unsigned long long lo[8], hi[8];
                #pragma unroll
                for (int dt = 0; dt < 8; ++dt) {
                    unsigned a = trbase + (unsigned)(kcp * 1024 + dt * 2048);
                    asm volatile("ds_read_b64_tr_b16 %0, %1" : "=v"(lo[dt]) : "v"(a));
                    asm volatile("ds_read_b64_tr_b16 %0, %1 offset:128" : "=v"(hi[dt]) : "v"(a));
                }
                asm volatile("s_waitcnt lgkmcnt(0)" ::: "memory");
                __builtin_amdgcn_sched_barrier(0);
                #pragma unroll
                for (int dt = 0; dt < 8; ++dt) {
                    union { unsigned long long u[2]; short8v s; } fr;
                    fr.u[0] = lo[dt]; fr.u[1] = hi[dt];
                    yacc[dt] = __builtin_amdgcn_mfma_f32_16x16x32_bf16(pa, fr.s, yacc[dt], 0, 0, 0);
                }
            }
        }

        __syncthreads();
        cur ^= 1;
    }

    // ---- final sum reduce (once) ----
    float lrun[4];
    #pragma unroll
    for (int rg = 0; rg < 4; ++rg) {
        float ts = lsum[rg];
        ts += __shfl_xor(ts, 1, 64);
        ts += __shfl_xor(ts, 2, 64);
        ts += __shfl_xor(ts, 4, 64);
        ts += __shfl_xor(ts, 8, 64);
        lrun[rg] = ts;
    }

    // ---- merge halves in LDS ----
    float* ys = (float*)&KsBuf[0][0][0];
    if (half == 1) {
        #pragma unroll
        for (int rg = 0; rg < 4; ++rg) {
            #pragma unroll
            for (int dt = 0; dt < 8; ++dt)
                ys[wq * 2048 + (4 * g + rg) * 128 + 16 * dt + c15] = yacc[dt][rg];
            if (c15 == 0) {
                mlS[wq][4 * g + rg][0] = mrun[rg];
                mlS[wq][4 * g + rg][1] = lrun[rg];
            }
        }
    }
    __syncthreads();
    if (half == 0) {
        #pragma unroll
        for (int rg = 0; rg < 4; ++rg) {
            float m1 = mlS[wq][4 * g + rg][0];
            float l1 = mlS[wq][4 * g + rg][1];
            float M  = fmaxf(mrun[rg], m1);
            float w0 = __expf(mrun[rg] - M);
            float w1 = __expf(m1 - M);
            float inv = 1.f / (lrun[rg] * w0 + l1 * w1);
            int row = qrow0 + 4 * g + rg;
            int cch = row >> 2, t = row & 3;
            int ctile = cch >> 6, crow = cch & 63;
            #pragma unroll
            for (int dt = 0; dt < 8; ++dt) {
                float v = (yacc[dt][rg] * w0 + ys[wq * 2048 + (4 * g + rg) * 128 + 16 * dt + c15] * w1) * inv;
                int pos = t * 128 + dt * 16 + c15;
                ybf[(size_t)((bb * 16 + ctile) * 8 + (pos >> 6)) * 4096 +
                    ((pos >> 4) & 3) * 1024 + crow * 16 + (pos & 15)] = f2bf(v);
            }
        }
    }
}

// ---- 2) y1 = W1 @ Y via bf16 MFMA; K-chunk 128; fused BN partial stats ------
// grid 512 = ot(16) x pt(8) x b(4); block 256.
__global__ __launch_bounds__(256, 2) void k_w1_mfma(const short* __restrict__ ybf,
                                                    const short* __restrict__ wbf,
                                                    float* __restrict__ y1,
                                                    float* __restrict__ stat)
{
    __shared__ short Kw[2][8192];   // [buf][2 ctile][4 psub][64 c][16 pos] 32 KB
    const int tid = threadIdx.x, lane = tid & 63, wid = tid >> 6;
    const int g = lane >> 4, c15 = lane & 15;
    const int b = blockIdx.x & 3, pt = (blockIdx.x >> 2) & 7, ot = blockIdx.x >> 5;

    f32x4 acc[4];
    const f32x4 z4 = {0.f, 0.f, 0.f, 0.f};
    #pragma unroll
    for (int dt = 0; dt < 4; ++dt) acc[dt] = z4;

    const unsigned trL = (unsigned)((8 * g + (c15 >> 2)) * 32 + (c15 & 3) * 8);
    const short* wrow = wbf + (size_t)(ot * 64 + wid * 16 + c15) * 1024;

    // prologue: stage c-chunk 0 (2 ctiles)
    {
        #pragma unroll
        for (int ct2 = 0; ct2 < 2; ++ct2) {
            const short* src = ybf + (size_t)((b * 16 + ct2) * 8 + pt) * 4096;
            #pragma unroll
            for (int i = 0; i < 2; ++i) {
                int off = ct2 * 4096 + wid * 1024 + i * 512;
                gload16((const char*)(src + (wid * 1024 + i * 512)) + lane * 16, &Kw[0][off]);
            }
        }
    }
    __syncthreads();

    int cur = 0;
    for (int cc = 0; cc < 8; ++cc) {
        if (cc < 7) {
            #pragma unroll
            for (int ct2 = 0; ct2 < 2; ++ct2) {
                const short* src = ybf + (size_t)((b * 16 + 2 * (cc + 1) + ct2) * 8 + pt) * 4096;
                #pragma unroll
                for (int i = 0; i < 2; ++i) {
                    int off = ct2 * 4096 + wid * 1024 + i * 512;
                    gload16((const char*)(src + (wid * 1024 + i * 512)) + lane * 16, &Kw[cur ^ 1][off]);
                }
            }
        }
        short8v af[4];
        #pragma unroll
        for (int kc = 0; kc < 4; ++kc)
            af[kc] = *(const short8v*)(wrow + cc * 128 + kc * 32 + 8 * g);

        unsigned kbase = (unsigned)(size_t)&Kw[cur][0];
        unsigned trbase = kbase + trL;
        #pragma unroll
        for (int ct2 = 0; ct2 < 2; ++ct2) {
            #pragma unroll
            for (int kcp = 0; kcp < 2; ++kcp) {
                unsigned long long lo[4], hi[4];
                #pragma unroll
                for (int dt = 0; dt < 4; ++dt) {
                    unsigned a = trbase + (unsigned)(ct2 * 8192 + kcp * 1024 + dt * 2048);
                    asm volatile("ds_read_b64_tr_b16 %0, %1" : "=v"(lo[dt]) : "v"(a));
                    asm volatile("ds_read_b64_tr_b16 %0, %1 offset:128" : "=v"(hi[dt]) : "v"(a));
                }
                asm volatile("s_waitcnt lgkmcnt(0)" ::: "memory");
                __builtin_amdgcn_sched_barrier(0);
                #pragma unroll
                for (int dt = 0; dt < 4; ++dt) {
                    union { unsigned long long u[2]; short8v s; } fr;
                    fr.u[0] = lo[dt]; fr.u[1] = hi[dt];
                    acc[dt] = __builtin_amdgcn_mfma_f32_16x16x32_bf16(af[ct2 * 2 + kcp], fr.s, acc[dt], 0, 0, 0);
                }
            }
        }
        __syncthreads();
        cur ^= 1;
    }

    const int o0 = ot * 64 + wid * 16 + 4 * g;
    #pragma unroll
    for (int dt = 0; dt < 4; ++dt)
        #pragma unroll
        for (int rg = 0; rg < 4; ++rg)
            y1[(size_t)(b * 1024 + o0 + rg) * 512 + pt * 64 + 16 * dt + c15] = acc[dt][rg];

    // fused BN partial stats: per-channel sum/sumsq over this block's 64 pos
    #pragma unroll
    for (int rg = 0; rg < 4; ++rg) {
        float s = acc[0][rg] + acc[1][rg] + acc[2][rg] + acc[3][rg];
        float q = acc[0][rg] * acc[0][rg] + acc[1][rg] * acc[1][rg] +
                  acc[2][rg] * acc[2][rg] + acc[3][rg] * acc[3][rg];
        s += __shfl_xor(s, 1, 64); q += __shfl_xor(q, 1, 64);
        s += __shfl_xor(s, 2, 64); q += __shfl_xor(q, 2, 64);
        s += __shfl_xor(s, 4, 64); q += __shfl_xor(q, 4, 64);
        s += __shfl_xor(s, 8, 64); q += __shfl_xor(q, 8, 64);
        if (c15 == 0) {
            atomicAdd(stat + o0 + rg, s);
            atomicAdd(stat + 1024 + o0 + rg, q);
        }
    }
}

// ---- 4) z = bn(y1)+x ; u[b,c] into A rows 64..67 (stats finalized inline) ---
__global__ __launch_bounds__(128) void k_zu(const float* __restrict__ y1, const float* __restrict__ x,
                                            const float* __restrict__ stat, const float* __restrict__ g,
                                            const float* __restrict__ beta, float* __restrict__ z,
                                            float* __restrict__ A)
{
    const int blk = blockIdx.x;
    const int b = blk >> 10, o = blk & 1023;
    const int tid = threadIdx.x;
    float m = stat[o] * (1.f / 2048.f);
    float var = stat[1024 + o] * (1.f / 2048.f) - m * m;
    float rs = rsqrtf(var + EPSBN) * g[o];
    float bt = beta[o] - m * rs;
    size_t base = (size_t)blk * 512;
    float sum = 0.f;
    #pragma unroll
    for (int it = 0; it < 4; ++it) {
        int j = it * 128 + tid;
        float v = y1[base + j] * rs + bt + x[base + j];
        z[base + j] = v;
        sum += v;
    }
    #pragma unroll
    for (int off = 32; off > 0; off >>= 1) sum += __shfl_down(sum, off, 64);
    __shared__ float red[2];
    if ((tid & 63) == 0) red[tid >> 6] = sum;
    __syncthreads();
    if (tid == 0) A[(size_t)(64 + b) * 1024 + o] = (red[0] + red[1]) * (1.f / 512.f);
}

// ---- 5) spatial-attn partial: sapart[cq][bt][n][p] --------------------------
__global__ __launch_bounds__(256) void k_sap(const float* __restrict__ z, const float* __restrict__ saw,
                                             float* __restrict__ sapart)
{
    const int bt = blockIdx.x >> 2, cq = blockIdx.x & 3;
    const int b = bt >> 2, t = bt & 3;
    const int tid = threadIdx.x;
    __shared__ float wsm[4][256];
    __shared__ float part[2][4][128];
    #pragma unroll
    for (int it = 0; it < 4; ++it) {
        int e = it * 256 + tid;
        wsm[e >> 8][e & 255] = saw[(e >> 8) * 1024 + cq * 256 + (e & 255)];
    }
    __syncthreads();
    const int p = tid & 127, half = tid >> 7;
    float a0 = 0, a1 = 0, a2 = 0, a3 = 0;
    for (int ci = 0; ci < 128; ++ci) {
        int cl = half * 128 + ci;
        float zv = z[(size_t)(b * 1024 + cq * 256 + cl) * 512 + t * 128 + p];
        a0 += zv * wsm[0][cl]; a1 += zv * wsm[1][cl];
        a2 += zv * wsm[2][cl]; a3 += zv * wsm[3][cl];
    }
    part[half][0][p] = a0; part[half][1][p] = a1;
    part[half][2][p] = a2; part[half][3][p] = a3;
    __syncthreads();
    #pragma unroll
    for (int it = 0; it < 2; ++it) {
        int e = it * 256 + tid;
        int n = e >> 7, pp = e & 127;
        sapart[(size_t)((cq * 16 + bt) * 4 + n) * 128 + pp] = part[0][n][pp] + part[1][n][pp];
    }
}

// ---- 6) fused: reduce partials -> stats -> sigmoid(bn) -> aw + aout ---------
// grid 4 (n), block 256
__global__ __launch_bounds__(256) void k_sastat(const float* __restrict__ sapart,
                                                const float* __restrict__ sag, const float* __restrict__ sabeta,
                                                float* __restrict__ aw, float* __restrict__ aout)
{
    const int n = blockIdx.x;
    const int tid = threadIdx.x;
    float vreg[8];
    float s = 0.f, q = 0.f;
    #pragma unroll
    for (int it = 0; it < 8; ++it) {
        int e = it * 256 + tid;           // bt*128 + p
        int bt = e >> 7, p = e & 127;
        float v = 0.f;
        #pragma unroll
        for (int cq = 0; cq < 4; ++cq)
            v += sapart[(size_t)((cq * 16 + bt) * 4 + n) * 128 + p];
        vreg[it] = v;
        s += v; q += v * v;
    }
    #pragma unroll
    for (int off = 32; off > 0; off >>= 1) { s += __shfl_down(s, off, 64); q += __shfl_down(q, off, 64); }
    __shared__ float ss[4], qq[4], bc[2];
    if ((tid & 63) == 0) { ss[tid >> 6] = s; qq[tid >> 6] = q; }
    __syncthreads();
    if (tid == 0) {
        float S = ss[0] + ss[1] + ss[2] + ss[3];
        float Q = qq[0] + qq[1] + qq[2] + qq[3];
        float m = S * (1.f / 2048.f);
        float var = Q * (1.f / 2048.f) - m * m;
        bc[0] = m;
        bc[1] = rsqrtf(var + EPSBN);
    }
    __syncthreads();
    float m = bc[0], rsg = bc[1] * sag[n], be = sabeta[n];
    #pragma unroll
    for (int it = 0; it < 8; ++it) {
        int e = it * 256 + tid;
        int bt = e >> 7, p = e & 127;
        int b = bt >> 2, t = bt & 3;
        float val = (vreg[it] - m) * rsg + be;
        float sig = 1.f / (1.f + __expf(-val));
        aw[(size_t)((b * 4 + n) * 4 + t) * 128 + p] = sig;
        aout[(size_t)((b * 4 + t) * 4 + n) * 128 + p] = sig;
    }
}

// ---- 8) parts[b,t,n,c] into A rows 0..63 -----------------------------------
__global__ __launch_bounds__(256) void k_parts(const float* __restrict__ z, const float* __restrict__ aw,
                                               float* __restrict__ A)
{
    const int bt = blockIdx.x >> 2, cq = blockIdx.x & 3;
    const int b = bt >> 2, t = bt & 3;
    const int tid = threadIdx.x;
    __shared__ float As[4][132];
    __shared__ float Zs[64][132];
    #pragma unroll
    for (int it = 0; it < 2; ++it) {
        int e = it * 256 + tid;
        int n = e >> 7, p = e & 127;
        As[n][p] = aw[(size_t)((b * 4 + n) * 4 + t) * 128 + p];
    }
    const int cl = tid >> 2, n = tid & 3;
    for (int c0 = cq * 256; c0 < cq * 256 + 256; c0 += 64) {
        #pragma unroll
        for (int it = 0; it < 8; ++it) {
            int e = (it * 256 + tid) * 4;
            int r = e >> 7, cc = e & 127;
            *(float4*)&Zs[r][cc] = *(const float4*)(z + (size_t)(b * 1024 + c0 + r) * 512 + t * 128 + cc);
        }
        __syncthreads();
        float acc = 0.f;
        #pragma unroll
        for (int k4 = 0; k4 < 32; ++k4) {
            float4 zv = *(const float4*)&Zs[cl][4 * k4];
            float4 av = *(const float4*)&As[n][4 * k4];
            acc += zv.x * av.x + zv.y * av.y + zv.z * av.z + zv.w * av.w;
        }
        A[(size_t)(b * 16 + t * 4 + n) * 1024 + c0 + cl] = acc;
        __syncthreads();
    }
}

// ---- 9) reduce_dimension: NB[68][512] = A @ g_w^T + g_b --------------------
__global__ __launch_bounds__(256) void k_rd(const float* __restrict__ A, const float* __restrict__ gw,
                                            const float* __restrict__ gb, float* __restrict__ NB)
{
    int flat = blockIdx.x * 256 + threadIdx.x;
    int row = flat >> 9, o = flat & 511;
    const float4* a4 = (const float4*)(A + (size_t)row * 1024);
    const float4* w4 = (const float4*)(gw + (size_t)o * 1024);
    float acc = 0.f;
    for (int k = 0; k < 256; ++k) {
        float4 av = a4[k], wv = w4[k];
        acc += av.x * wv.x + av.y * wv.y + av.z * wv.z + av.w * wv.w;
    }
    NB[flat] = acc + gb[o];
}

// ---- 10) nodes = parts_r + u_r @ wu ; grid 32 = b(4) x oc(8) ---------------
__global__ __launch_bounds__(256) void k_nodes(const float* __restrict__ NB, const float* __restrict__ wu,
                                               float* __restrict__ nodes)
{
    const int b = blockIdx.x >> 3, oc = blockIdx.x & 7;
    const int tid = threadIdx.x;
    __shared__ float us[512];
    __shared__ float part[4][64];
    __shared__ float uwu[64];
    us[tid] = NB[(size_t)(64 + b) * 512 + tid];
    us[tid + 256] = NB[(size_t)(64 + b) * 512 + tid + 256];
    __syncthreads();
    const int ol = tid & 63, qd = tid >> 6;
    const int o = oc * 64 + ol;
    float acc = 0.f;
    for (int k = qd * 128; k < qd * 128 + 128; ++k)
        acc += us[k] * wu[(size_t)k * 512 + o];
    part[qd][ol] = acc;
    __syncthreads();
    if (tid < 64) uwu[tid] = part[0][tid] + part[1][tid] + part[2][tid] + part[3][tid];
    __syncthreads();
    #pragma unroll
    for (int it = 0; it < 4; ++it) {
        int e = it * 256 + tid;          // j*64 + ol
        int j = e >> 6, o2 = e & 63;
        nodes[(size_t)b * 8192 + (size_t)j * 512 + oc * 64 + o2] =
            NB[(size_t)(b * 16 + j) * 512 + oc * 64 + o2] + uwu[o2];
    }
}

// ---- 11) qt/pp/gg = nodes @ {wt,wp,wg} -------------------------------------
__global__ __launch_bounds__(256) void k_qpg(const float* __restrict__ nodes, const float* __restrict__ wt,
                                             const float* __restrict__ wp, const float* __restrict__ wg,
                                             float* __restrict__ qpg)
{
    const int b = blockIdx.x / 12;
    const int r = blockIdx.x % 12;
    const int m = r >> 2;
    const int o0 = (r & 3) * 128;
    const float* W = (m == 0) ? wt : (m == 1) ? wp : wg;
    const int tid = threadIdx.x;
    __shared__ float ns[16][512];
    #pragma unroll
    for (int it = 0; it < 32; ++it) {
        int e = it * 256 + tid;
        ns[e >> 9][e & 511] = nodes[(size_t)b * 8192 + e];
    }
    __syncthreads();
    const int o = o0 + (tid & 127);
    const int jg = tid >> 7;
    float acc[8];
    #pragma unroll
    for (int jj = 0; jj < 8; ++jj) acc[jj] = 0.f;
    for (int k4 = 0; k4 < 128; ++k4) {
        float w0 = W[(size_t)(4 * k4 + 0) * 512 + o];
        float w1 = W[(size_t)(4 * k4 + 1) * 512 + o];
        float w2 = W[(size_t)(4 * k4 + 2) * 512 + o];
        float w3 = W[(size_t)(4 * k4 + 3) * 512 + o];
        #pragma unroll
        for (int jj = 0; jj < 8; ++jj) {
            float4 nv = *(const float4*)&ns[jg * 8 + jj][4 * k4];
            acc[jj] += nv.x * w0 + nv.y * w1 + nv.z * w2 + nv.w * w3;
        }
    }
    #pragma unroll
    for (int jj = 0; jj < 8; ++jj)
        qpg[(size_t)((m * 4 + b) * 16 + jg * 8 + jj) * 512 + o] = acc[jj];
}

// ---- 12) STIAU attention + aggregate + cat ---------------------------------
__global__ __launch_bounds__(256) void k_stiau(const float* __restrict__ nodes, const float* __restrict__ qpg,
                                               const float* __restrict__ NB, float* __restrict__ cat)
{
    const int b = blockIdx.x;
    const int tid = threadIdx.x;
    __shared__ float q_s[16][516];
    __shared__ float p_s[16][516];
    __shared__ float att[16][17];
    #pragma unroll
    for (int it = 0; it < 32; ++it) {
        int e = it * 256 + tid;
        int j = e >> 9, k = e & 511;
        q_s[j][k] = qpg[(size_t)(0 * 4 + b) * 8192 + e];
        p_s[j][k] = qpg[(size_t)(1 * 4 + b) * 8192 + e];
    }
    __syncthreads();
    const int j = tid >> 4, mm = tid & 15;
    float acc = 0.f;
    #pragma unroll
    for (int k4 = 0; k4 < 128; ++k4) {
        float4 qv = *(const float4*)&q_s[j][4 * k4];
        float4 pv = *(const float4*)&p_s[mm][4 * k4];
        acc += qv.x * pv.x + qv.y * pv.y + qv.z * pv.z + qv.w * pv.w;
    }
    acc *= 0.04419417382415922f;
    float mx = acc;
    #pragma unroll
    for (int off = 1; off < 16; off <<= 1) mx = fmaxf(mx, __shfl_xor(mx, off, 64));
    float ev = __expf(acc - mx);
    float sm = ev;
    #pragma unroll
    for (int off = 1; off < 16; off <<= 1) sm += __shfl_xor(sm, off, 64);
    att[j][mm] = ev / sm;
    __syncthreads();
    #pragma unroll
    for (int it = 0; it < 32; ++it) {
        int e = it * 256 + tid;
        q_s[e >> 9][e & 511] = qpg[(size_t)(2 * 4 + b) * 8192 + e];
    }
    __syncthreads();
    #pragma unroll
    for (int it = 0; it < 32; ++it) {
        int e = it * 256 + tid;
        int jj = e >> 9, o = e & 511;
        float v = nodes[(size_t)b * 8192 + e];
        #pragma unroll
        for (int m2 = 0; m2 < 16; ++m2) v += att[jj][m2] * q_s[m2][o];
        p_s[jj][o] = v;
    }
    __syncthreads();
    #pragma unroll
    for (int it = 0; it < 16; ++it) {
        int e = it * 256 + tid;
        int t = e >> 10, cc = e & 1023;
        float val;
        if (cc < 512)
            val = 0.25f * (p_s[t * 4 + 0][cc] + p_s[t * 4 + 1][cc] + p_s[t * 4 + 2][cc] + p_s[t * 4 + 3][cc]);
        else
            val = NB[(size_t)(64 + b) * 512 + (cc - 512)];
        cat[(size_t)(b * 4 + t) * 1024 + cc] = val;
    }
}

// ---- 13) out0[b,o,t] = cat[b,t,:] . w2_w[o,:] ------------------------------
__global__ __launch_bounds__(256) void k_w2(const float* __restrict__ cat, const float* __restrict__ w2w,
                                            float* __restrict__ out0)
{
    int flat = blockIdx.x * 256 + threadIdx.x;
    int b = flat >> 12, o = (flat >> 2) & 1023, t = flat & 3;
    const float4* c4 = (const float4*)(cat + (size_t)(b * 4 + t) * 1024);
    const float4* w4 = (const float4*)(w2w + (size_t)o * 1024);
    float acc = 0.f;
    for (int k = 0; k < 256; ++k) {
        float4 cv = c4[k], wv = w4[k];
        acc += cv.x * wv.x + cv.y * wv.y + cv.z * wv.z + cv.w * wv.w;
    }
    out0[flat] = acc;
}

// ---- 14) BN over (b,t)=16 per channel; z_out = bn(out0) + z ----------------
__global__ __launch_bounds__(256) void k_bn2out(const float* __restrict__ out0, const float* __restrict__ g,
                                                const float* __restrict__ beta, const float* __restrict__ z,
                                                float* __restrict__ zout)
{
    const int o = blockIdx.x;
    const int tid = threadIdx.x;
    __shared__ float bnv[16];
    if (tid == 0) {
        float s = 0.f, q = 0.f, vals[16];
        #pragma unroll
        for (int i = 0; i < 16; ++i) {
            int b = i >> 2, t = i & 3;
            float v = out0[(size_t)(b * 1024 + o) * 4 + t];
            vals[i] = v; s += v; q += v * v;
        }
        float m = s * (1.f / 16.f);
        float var = q * (1.f / 16.f) - m * m;
        float rs = rsqrtf(var + EPSBN) * g[o];
        float bb = beta[o] - m * rs;
        #pragma unroll
        for (int i = 0; i < 16; ++i) bnv[i] = vals[i] * rs + bb;
    }
    __syncthreads();
    #pragma unroll
    for (int it = 0; it < 8; ++it) {
        int e = it * 256 + tid;
        int bt = e >> 7, p = e & 127;
        int b = bt >> 2, t = bt & 3;
        size_t idx = (size_t)(b * 1024 + o) * 512 + t * 128 + p;
        zout[idx] = z[idx] + bnv[bt];
    }
}

extern "C" void kernel_launch(void* const* d_in, const int* in_sizes, int n_in,
                              void* d_out, int out_size, void* d_ws, size_t ws_size,
                              hipStream_t stream)
{
    const float* x      = (const float*)d_in[0];
    const float* sa_w   = (const float*)d_in[1];
    const float* sa_g   = (const float*)d_in[3];
    const float* sa_be  = (const float*)d_in[4];
    const float* g_w    = (const float*)d_in[5];
    const float* g_b    = (const float*)d_in[6];
    const float* w1_w   = (const float*)d_in[7];
    const float* w1_g   = (const float*)d_in[9];
    const float* w1_be  = (const float*)d_in[10];
    const float* w2_w   = (const float*)d_in[11];
    const float* w2_g   = (const float*)d_in[13];
    const float* w2_be  = (const float*)d_in[14];
    const float* wt     = (const float*)d_in[15];
    const float* wp     = (const float*)d_in[16];
    const float* wg     = (const float*)d_in[17];
    const float* wu     = (const float*)d_in[18];
    float* out = (float*)d_out;
    float* ws  = (float*)d_ws;
    if (ws_size < (size_t)WS_FLOATS * sizeof(float)) return;  // fail loudly

    short* YBF  = (short*)(ws + OFF_Y);
    short* XBF  = (short*)(ws + OFF_Y + 1048576);
    short* WBF  = (short*)(ws + OFF_Z);
    float* Y1   = ws + OFF_Y1;
    float* Z    = ws + OFF_Z;
    float* BN1  = ws + OFF_BN1;
    float* A    = ws + OFF_A;
    float* NBm  = ws + OFF_NB;
    float* NOD  = ws + OFF_NODES;
    float* QPG  = ws + OFF_QPG;
    float* CAT  = ws + OFF_CAT;
    float* OUT0 = ws + OFF_OUT0;
    float* AW   = ws + OFF_AW;
    float* SAPART = ws + OFF_Y;
    float* AOUT = out + 2097152;

    hipMemsetAsync(BN1, 0, 2048 * sizeof(float), stream);
    hipLaunchKernelGGL(k_prep,      dim3(12288), dim3(256), 0, stream, x, w1_w, XBF, WBF);
    hipLaunchKernelGGL(k_attn_mfma, dim3(256),   dim3(512), 0, stream, XBF, YBF);
    hipLaunchKernelGGL(k_w1_mfma,   dim3(512),   dim3(256), 0, stream, YBF, WBF, Y1, BN1);
    hipLaunchKernelGGL(k_zu,        dim3(4096),  dim3(128), 0, stream, Y1, x, BN1, w1_g, w1_be, Z, A);
    hipLaunchKernelGGL(k_sap,       dim3(64),    dim3(256), 0, stream, Z, sa_w, SAPART);
    hipLaunchKernelGGL(k_sastat,    dim3(4),     dim3(256), 0, stream, SAPART, sa_g, sa_be, AW, AOUT);
    hipLaunchKernelGGL(k_parts,     dim3(64),    dim3(256), 0, stream, Z, AW, A);
    hipLaunchKernelGGL(k_rd,        dim3(136),   dim3(256), 0, stream, A, g_w, g_b, NBm);
    hipLaunchKernelGGL(k_nodes,     dim3(32),    dim3(256), 0, stream, NBm, wu, NOD);
    hipLaunchKernelGGL(k_qpg,       dim3(48),    dim3(256), 0, stream, NOD, wt, wp, wg, QPG);
    hipLaunchKernelGGL(k_stiau,     dim3(4),     dim3(256), 0, stream, NOD, QPG, NBm, CAT);
    hipLaunchKernelGGL(k_w2,        dim3(64),    dim3(256), 0, stream, CAT, w2_w, OUT0);
    hipLaunchKernelGGL(k_bn2out,    dim3(1024),  dim3(256), 0, stream, OUT0, w2_g, w2_be, Z, out);
}

// Round 5
// 252.015 us; speedup vs baseline: 3.9388x; 1.0390x over previous
//
#include <hip/hip_runtime.h>
#include <math.h>

#define EPSBN 1e-5f

typedef __attribute__((ext_vector_type(4))) float f32x4;
typedef __attribute__((ext_vector_type(8))) short short8v;
typedef __attribute__((ext_vector_type(4))) short short4v;

__device__ __forceinline__ short f2bf(float f) {
    unsigned u = __float_as_uint(f);
    u = (u + 0x7FFFu + ((u >> 16) & 1u)) >> 16;
    return (short)u;
}

__device__ __forceinline__ void gload16(const void* gp, void* lp) {
    __builtin_amdgcn_global_load_lds(
        (const __attribute__((address_space(1))) unsigned int*)gp,
        (__attribute__((address_space(3))) unsigned int*)lp, 16, 0, 0);
}

// ---- workspace layout (float offsets) --------------------------------------
#define OFF_Y     0          // [0,1048576): Ybf (bf16 perm) ; [1048576,2097152): xbf (bf16 perm)
                             // after k_w1: reused as SAPART (131072 floats)
#define OFF_Y1    2097152    // y1 = w1 conv output, f32 (2097152)
#define OFF_Z     4194304    // first: wbf (bf16, 1048576 shorts); then z f32 (2097152)
#define OFF_BN1   6291456    // sum[1024], sumsq[1024]  (zeroed by k_prep tail blocks)
#define OFF_A     6301704    // A matrix 68x1024
#define OFF_NB    6371336    // reduced 68x512
#define OFF_NODES 6406152    // nodes 4x16x512
#define OFF_QPG   6438920    // qt,pp,gg : 3x4x16x512
#define OFF_CAT   6537224    // cat 4x4x1024
#define OFF_AW    6569992    // sigmoid a (8192)
#define WS_FLOATS 6578184

// ---- 0) prep: x -> xbf (permuted), w1_w -> wbf, zero BN1 --------------------
// grid 12296 x 256
__global__ __launch_bounds__(256) void k_prep(const float* __restrict__ x, const float* __restrict__ w1w,
                                              short* __restrict__ xbf, short* __restrict__ wbf,
                                              float* __restrict__ bn1)
{
    int e = blockIdx.x * 256 + threadIdx.x;
    if (e < 2097152) {
        float v = x[e];
        int b = e >> 19, rem = e & 524287;
        int row = rem >> 7, p = rem & 127;
        xbf[b * 524288 + (row >> 6) * 8192 + (p >> 4) * 1024 + (row & 63) * 16 + (p & 15)] = f2bf(v);
    } else if (e < 3145728) {
        int e2 = e - 2097152;
        wbf[e2] = f2bf(w1w[e2]);
    } else {
        int i = e - 3145728;
        if (i < 2048) bn1[i] = 0.f;
    }
}

// ---- 1) non-local attention: bf16 MFMA flash, in-block KV split -------------
// Q pre-scaled by log2e (exp -> bare v_exp_f32); P -> bf16 via v_cvt_pk;
// lazy-max + deferred sum; diag-first rotation.
__global__ __launch_bounds__(512, 1) void k_attn_mfma(const short* __restrict__ xbf,
                                                      short* __restrict__ ybf)
{
    __shared__ short KsBuf[2][2][8192];   // [half][buf] 64 KB
    __shared__ short Pl[8][16 * 72];      // 18 KB
    __shared__ float mlS[4][16][2];

    const int tid  = threadIdx.x;
    const int lane = tid & 63;
    const int wid  = tid >> 6;
    const int half = wid >> 2;
    const int wq   = wid & 3;
    const int g    = lane >> 4;
    const int c15  = lane & 15;

    const int bswz = blockIdx.x;
    const int xcd  = bswz & 7;
    const int bb   = xcd >> 1;
    const int rb   = ((bswz >> 3) << 1) | (xcd & 1);

    const short* xb = xbf + (size_t)bb * 524288;

    const int qrow0 = rb * 64 + wq * 16;
    // Q fragments scaled by log2e so softmax exp is a bare v_exp_f32
    short8v qf[4];
    {
        const short* qp = xb + rb * 8192 + (g >> 1) * 1024 + (wq * 16 + c15) * 16 + (g & 1) * 8;
        #pragma unroll
        for (int kc = 0; kc < 4; ++kc) {
            short8v raw = *(const short8v*)(qp + kc * 2048);
            short8v q;
            #pragma unroll
            for (int j = 0; j < 8; ++j) {
                float f = __uint_as_float(((unsigned)(unsigned short)raw[j]) << 16) * 1.44269504f;
                q[j] = f2bf(f);
            }
            qf[kc] = q;
        }
    }

    f32x4 yacc[8];
    const f32x4 z4 = {0.f, 0.f, 0.f, 0.f};
    #pragma unroll
    for (int dt = 0; dt < 8; ++dt) yacc[dt] = z4;
    float mrun[4] = {-1e30f, -1e30f, -1e30f, -1e30f};
    float lsum[4] = {0.f, 0.f, 0.f, 0.f};

    const int qkb = (g >> 1) * 1024 + c15 * 16 + (g & 1) * 8;
    const unsigned trL = (unsigned)((8 * g + (c15 >> 2)) * 32 + (c15 & 3) * 8);

    const int t0 = half * 32;
    const int r0 = rb & 31;
    {
        const short* src = xb + (size_t)(t0 + r0) * 8192;
        #pragma unroll
        for (int i = 0; i < 4; ++i) {
            int off = wq * 2048 + i * 512;
            gload16((const char*)(src + off) + lane * 16, &KsBuf[half][0][off]);
        }
    }
    __syncthreads();

    int cur = 0;
    for (int tn = 0; tn < 32; ++tn) {
        if (tn < 31) {
            const short* src = xb + (size_t)(t0 + ((tn + 1 + r0) & 31)) * 8192;
            #pragma unroll
            for (int i = 0; i < 4; ++i) {
                int off = wq * 2048 + i * 512;
                gload16((const char*)(src + off) + lane * 16, &KsBuf[half][cur ^ 1][off]);
            }
        }

        const short* kb = &KsBuf[half][cur][0];

        // ---- QK^T (scores already in log2 domain via scaled Q) ----
        f32x4 sacc[4];
        #pragma unroll
        for (int nt = 0; nt < 4; ++nt) sacc[nt] = z4;
        #pragma unroll
        for (int kc = 0; kc < 4; ++kc) {
            #pragma unroll
            for (int nt = 0; nt < 4; ++nt) {
                short8v bf = *(const short8v*)&kb[qkb + kc * 2048 + nt * 256];
                sacc[nt] = __builtin_amdgcn_mfma_f32_16x16x32_bf16(qf[kc], bf, sacc[nt], 0, 0, 0);
            }
        }

        // ---- lazy max ----
        float lmax[4]; int upd = 0;
        #pragma unroll
        for (int rg = 0; rg < 4; ++rg) {
            lmax[rg] = fmaxf(fmaxf(sacc[0][rg], sacc[1][rg]), fmaxf(sacc[2][rg], sacc[3][rg]));
            upd |= (lmax[rg] > mrun[rg]) ? 1 : 0;
        }
        if (__any(upd)) {
            #pragma unroll
            for (int rg = 0; rg < 4; ++rg) {
                float v = lmax[rg];
                v = fmaxf(v, __shfl_xor(v, 1, 64));
                v = fmaxf(v, __shfl_xor(v, 2, 64));
                v = fmaxf(v, __shfl_xor(v, 4, 64));
                v = fmaxf(v, __shfl_xor(v, 8, 64));
                float mn = fmaxf(mrun[rg], v);
                float al = exp2f(mrun[rg] - mn);
                mrun[rg] = mn;
                lsum[rg] *= al;
                #pragma unroll
                for (int dt = 0; dt < 8; ++dt) yacc[dt][rg] *= al;
            }
        }
        #pragma unroll
        for (int rg = 0; rg < 4; ++rg) {
            float p0 = exp2f(sacc[0][rg] - mrun[rg]);
            float p1 = exp2f(sacc[1][rg] - mrun[rg]);
            float p2 = exp2f(sacc[2][rg] - mrun[rg]);
            float p3 = exp2f(sacc[3][rg] - mrun[rg]);
            unsigned pwb = (unsigned)(size_t)&Pl[wid][(4 * g + rg) * 72 + c15];
            unsigned pk01, pk23;
            asm("v_cvt_pk_bf16_f32 %0, %1, %2" : "=v"(pk01) : "v"(p0), "v"(p1));
            asm("v_cvt_pk_bf16_f32 %0, %1, %2" : "=v"(pk23) : "v"(p2), "v"(p3));
            asm volatile("ds_write_b16 %0, %1"                 :: "v"(pwb), "v"(pk01) : "memory");
            asm volatile("ds_write_b16_d16_hi %0, %1 offset:32" :: "v"(pwb), "v"(pk01) : "memory");
            asm volatile("ds_write_b16 %0, %1 offset:64"        :: "v"(pwb), "v"(pk23) : "memory");
            asm volatile("ds_write_b16_d16_hi %0, %1 offset:96" :: "v"(pwb), "v"(pk23) : "memory");
            lsum[rg] += (p0 + p1) + (p2 + p3);
        }
        // inline-asm ds_writes are untracked: fence before pa reads (rule 18)
        asm volatile("s_waitcnt lgkmcnt(0)" ::: "memory");
        __builtin_amdgcn_sched_barrier(0);

        // ---- PV via tr-read ----
        {
            unsigned kbase = (unsigned)(size_t)kb;
            unsigned trbase = kbase + trL;
            #pragma unroll
            for (int kcp = 0; kcp < 2; ++kcp) {
                short8v pa = *(const short8v*)&Pl[wid][c15 * 72 + kcp * 32 + 8 * g];
                unsigned long long lo[8], hi[8];
                #pragma unroll
                for (int dt = 0; dt < 8; ++dt) {
                    unsigned a = trbase + (unsigned)(kcp * 1024 + dt * 2048);
                    asm volatile("ds_read_b64_tr_b16 %0, %1" : "=v"(lo[dt]) : "v"(a));
                    asm volatile("ds_read_b64_tr_b16 %0, %1 offset:128" : "=v"(hi[dt]) : "v"(a));
                }
                asm volatile("s_waitcnt lgkmcnt(0)" ::: "memory");
                __builtin_amdgcn_sched_barrier(0);
                #pragma unroll
                for (int dt = 0; dt < 8; ++dt) {
                    union { unsigned long long u[2]; short8v s; } fr;
                    fr.u[0] = lo[dt]; fr.u[1] = hi[dt];
                    yacc[dt] = __builtin_amdgcn_mfma_f32_16x16x32_bf16(pa, fr.s, yacc[dt], 0, 0, 0);
                }
            }
        }

        __syncthreads();
        cur ^= 1;
    }

    // ---- final sum reduce ----
    float lrun[4];
    #pragma unroll
    for (int rg = 0; rg < 4; ++rg) {
        float ts = lsum[rg];
        ts += __shfl_xor(ts, 1, 64);
        ts += __shfl_xor(ts, 2, 64);
        ts += __shfl_xor(ts, 4, 64);
        ts += __shfl_xor(ts, 8, 64);
        lrun[rg] = ts;
    }

    // ---- merge halves in LDS ----
    float* ys = (float*)&KsBuf[0][0][0];
    if (half == 1) {
        #pragma unroll
        for (int rg = 0; rg < 4; ++rg) {
            #pragma unroll
            for (int dt = 0; dt < 8; ++dt)
                ys[wq * 2048 + (4 * g + rg) * 128 + 16 * dt + c15] = yacc[dt][rg];
            if (c15 == 0) {
                mlS[wq][4 * g + rg][0] = mrun[rg];
                mlS[wq][4 * g + rg][1] = lrun[rg];
            }
        }
    }
    __syncthreads();
    if (half == 0) {
        #pragma unroll
        for (int rg = 0; rg < 4; ++rg) {
            float m1 = mlS[wq][4 * g + rg][0];
            float l1 = mlS[wq][4 * g + rg][1];
            float M  = fmaxf(mrun[rg], m1);
            float w0 = exp2f(mrun[rg] - M);
            float w1 = exp2f(m1 - M);
            float inv = 1.f / (lrun[rg] * w0 + l1 * w1);
            int row = qrow0 + 4 * g + rg;
            int cch = row >> 2, t = row & 3;
            int ctile = cch >> 6, crow = cch & 63;
            #pragma unroll
            for (int dt = 0; dt < 8; ++dt) {
                float v = (yacc[dt][rg] * w0 + ys[wq * 2048 + (4 * g + rg) * 128 + 16 * dt + c15] * w1) * inv;
                int pos = t * 128 + dt * 16 + c15;
                ybf[(size_t)((bb * 16 + ctile) * 8 + (pos >> 6)) * 4096 +
                    ((pos >> 4) & 3) * 1024 + crow * 16 + (pos & 15)] = f2bf(v);
            }
        }
    }
}

// ---- 2) y1 = W1 @ Y via bf16 MFMA; K-chunk 128; fused BN partial stats ------
__global__ __launch_bounds__(256, 2) void k_w1_mfma(const short* __restrict__ ybf,
                                                    const short* __restrict__ wbf,
                                                    float* __restrict__ y1,
                                                    float* __restrict__ stat)
{
    __shared__ short Kw[2][8192];
    const int tid = threadIdx.x, lane = tid & 63, wid = tid >> 6;
    const int g = lane >> 4, c15 = lane & 15;
    const int b = blockIdx.x & 3, pt = (blockIdx.x >> 2) & 7, ot = blockIdx.x >> 5;

    f32x4 acc[4];
    const f32x4 z4 = {0.f, 0.f, 0.f, 0.f};
    #pragma unroll
    for (int dt = 0; dt < 4; ++dt) acc[dt] = z4;

    const unsigned trL = (unsigned)((8 * g + (c15 >> 2)) * 32 + (c15 & 3) * 8);
    const short* wrow = wbf + (size_t)(ot * 64 + wid * 16 + c15) * 1024;

    {
        #pragma unroll
        for (int ct2 = 0; ct2 < 2; ++ct2) {
            const short* src = ybf + (size_t)((b * 16 + ct2) * 8 + pt) * 4096;
            #pragma unroll
            for (int i = 0; i < 2; ++i) {
                int off = ct2 * 4096 + wid * 1024 + i * 512;
                gload16((const char*)(src + (wid * 1024 + i * 512)) + lane * 16, &Kw[0][off]);
            }
        }
    }
    __syncthreads();

    int cur = 0;
    for (int cc = 0; cc < 8; ++cc) {
        if (cc < 7) {
            #pragma unroll
            for (int ct2 = 0; ct2 < 2; ++ct2) {
                const short* src = ybf + (size_t)((b * 16 + 2 * (cc + 1) + ct2) * 8 + pt) * 4096;
                #pragma unroll
                for (int i = 0; i < 2; ++i) {
                    int off = ct2 * 4096 + wid * 1024 + i * 512;
                    gload16((const char*)(src + (wid * 1024 + i * 512)) + lane * 16, &Kw[cur ^ 1][off]);
                }
            }
        }
        short8v af[4];
        #pragma unroll
        for (int kc = 0; kc < 4; ++kc)
            af[kc] = *(const short8v*)(wrow + cc * 128 + kc * 32 + 8 * g);

        unsigned kbase = (unsigned)(size_t)&Kw[cur][0];
        unsigned trbase = kbase + trL;
        #pragma unroll
        for (int ct2 = 0; ct2 < 2; ++ct2) {
            #pragma unroll
            for (int kcp = 0; kcp < 2; ++kcp) {
                unsigned long long lo[4], hi[4];
                #pragma unroll
                for (int dt = 0; dt < 4; ++dt) {
                    unsigned a = trbase + (unsigned)(ct2 * 8192 + kcp * 1024 + dt * 2048);
                    asm volatile("ds_read_b64_tr_b16 %0, %1" : "=v"(lo[dt]) : "v"(a));
                    asm volatile("ds_read_b64_tr_b16 %0, %1 offset:128" : "=v"(hi[dt]) : "v"(a));
                }
                asm volatile("s_waitcnt lgkmcnt(0)" ::: "memory");
                __builtin_amdgcn_sched_barrier(0);
                #pragma unroll
                for (int dt = 0; dt < 4; ++dt) {
                    union { unsigned long long u[2]; short8v s; } fr;
                    fr.u[0] = lo[dt]; fr.u[1] = hi[dt];
                    acc[dt] = __builtin_amdgcn_mfma_f32_16x16x32_bf16(af[ct2 * 2 + kcp], fr.s, acc[dt], 0, 0, 0);
                }
            }
        }
        __syncthreads();
        cur ^= 1;
    }

    const int o0 = ot * 64 + wid * 16 + 4 * g;
    #pragma unroll
    for (int dt = 0; dt < 4; ++dt)
        #pragma unroll
        for (int rg = 0; rg < 4; ++rg)
            y1[(size_t)(b * 1024 + o0 + rg) * 512 + pt * 64 + 16 * dt + c15] = acc[dt][rg];

    #pragma unroll
    for (int rg = 0; rg < 4; ++rg) {
        float s = acc[0][rg] + acc[1][rg] + acc[2][rg] + acc[3][rg];
        float q = acc[0][rg] * acc[0][rg] + acc[1][rg] * acc[1][rg] +
                  acc[2][rg] * acc[2][rg] + acc[3][rg] * acc[3][rg];
        s += __shfl_xor(s, 1, 64); q += __shfl_xor(q, 1, 64);
        s += __shfl_xor(s, 2, 64); q += __shfl_xor(q, 2, 64);
        s += __shfl_xor(s, 4, 64); q += __shfl_xor(q, 4, 64);
        s += __shfl_xor(s, 8, 64); q += __shfl_xor(q, 8, 64);
        if (c15 == 0) {
            atomicAdd(stat + o0 + rg, s);
            atomicAdd(stat + 1024 + o0 + rg, q);
        }
    }
}

// ---- 4) z = bn(y1)+x ; u[b,c] into A rows 64..67 ---------------------------
__global__ __launch_bounds__(128) void k_zu(const float* __restrict__ y1, const float* __restrict__ x,
                                            const float* __restrict__ stat, const float* __restrict__ g,
                                            const float* __restrict__ beta, float* __restrict__ z,
                                            float* __restrict__ A)
{
    const int blk = blockIdx.x;
    const int b = blk >> 10, o = blk & 1023;
    const int tid = threadIdx.x;
    float m = stat[o] * (1.f / 2048.f);
    float var = stat[1024 + o] * (1.f / 2048.f) - m * m;
    float rs = rsqrtf(var + EPSBN) * g[o];
    float bt = beta[o] - m * rs;
    size_t base = (size_t)blk * 512;
    float sum = 0.f;
    #pragma unroll
    for (int it = 0; it < 4; ++it) {
        int j = it * 128 + tid;
        float v = y1[base + j] * rs + bt + x[base + j];
        z[base + j] = v;
        sum += v;
    }
    #pragma unroll
    for (int off = 32; off > 0; off >>= 1) sum += __shfl_down(sum, off, 64);
    __shared__ float red[2];
    if ((tid & 63) == 0) red[tid >> 6] = sum;
    __syncthreads();
    if (tid == 0) A[(size_t)(64 + b) * 1024 + o] = (red[0] + red[1]) * (1.f / 512.f);
}

// ---- 5) spatial-attn partial: grid 256 = bt(16) x cq(16), chunk 64 ----------
__global__ __launch_bounds__(256) void k_sap(const float* __restrict__ z, const float* __restrict__ saw,
                                             float* __restrict__ sapart)
{
    const int bt = blockIdx.x >> 4, cq = blockIdx.x & 15;
    const int b = bt >> 2, t = bt & 3;
    const int tid = threadIdx.x;
    __shared__ float wsm[4][64];
    __shared__ float part[2][4][128];
    wsm[tid >> 6][tid & 63] = saw[(tid >> 6) * 1024 + cq * 64 + (tid & 63)];
    __syncthreads();
    const int p = tid & 127, half = tid >> 7;
    float a0 = 0, a1 = 0, a2 = 0, a3 = 0;
    #pragma unroll
    for (int ci = 0; ci < 32; ++ci) {
        int cl = half * 32 + ci;
        float zv = z[(size_t)(b * 1024 + cq * 64 + cl) * 512 + t * 128 + p];
        a0 += zv * wsm[0][cl]; a1 += zv * wsm[1][cl];
        a2 += zv * wsm[2][cl]; a3 += zv * wsm[3][cl];
    }
    part[half][0][p] = a0; part[half][1][p] = a1;
    part[half][2][p] = a2; part[half][3][p] = a3;
    __syncthreads();
    #pragma unroll
    for (int it = 0; it < 2; ++it) {
        int e = it * 256 + tid;
        int n = e >> 7, pp = e & 127;
        sapart[(size_t)((cq * 16 + bt) * 4 + n) * 128 + pp] = part[0][n][pp] + part[1][n][pp];
    }
}

// ---- 6) fused: reduce partials -> stats -> sigmoid(bn) -> aw + aout ---------
__global__ __launch_bounds__(256) void k_sastat(const float* __restrict__ sapart,
                                                const float* __restrict__ sag, const float* __restrict__ sabeta,
                                                float* __restrict__ aw, float* __restrict__ aout)
{
    const int n = blockIdx.x;
    const int tid = threadIdx.x;
    float vreg[8];
    float s = 0.f, q = 0.f;
    #pragma unroll
    for (int it = 0; it < 8; ++it) {
        int e = it * 256 + tid;
        int bt = e >> 7, p = e & 127;
        float v = 0.f;
        #pragma unroll
        for (int cq = 0; cq < 16; ++cq)
            v += sapart[(size_t)((cq * 16 + bt) * 4 + n) * 128 + p];
        vreg[it] = v;
        s += v; q += v * v;
    }
    #pragma unroll
    for (int off = 32; off > 0; off >>= 1) { s += __shfl_down(s, off, 64); q += __shfl_down(q, off, 64); }
    __shared__ float ss[4], qq[4], bc[2];
    if ((tid & 63) == 0) { ss[tid >> 6] = s; qq[tid >> 6] = q; }
    __syncthreads();
    if (tid == 0) {
        float S = ss[0] + ss[1] + ss[2] + ss[3];
        float Q = qq[0] + qq[1] + qq[2] + qq[3];
        float m = S * (1.f / 2048.f);
        float var = Q * (1.f / 2048.f) - m * m;
        bc[0] = m;
        bc[1] = rsqrtf(var + EPSBN);
    }
    __syncthreads();
    float m = bc[0], rsg = bc[1] * sag[n], be = sabeta[n];
    #pragma unroll
    for (int it = 0; it < 8; ++it) {
        int e = it * 256 + tid;
        int bt = e >> 7, p = e & 127;
        int b = bt >> 2, t = bt & 3;
        float val = (vreg[it] - m) * rsg + be;
        float sig = 1.f / (1.f + __expf(-val));
        aw[(size_t)((b * 4 + n) * 4 + t) * 128 + p] = sig;
        aout[(size_t)((b * 4 + t) * 4 + n) * 128 + p] = sig;
    }
}

// ---- 8) parts into A rows 0..63: grid 256 = bt(16) x cq(16) -----------------
__global__ __launch_bounds__(256) void k_parts(const float* __restrict__ z, const float* __restrict__ aw,
                                               float* __restrict__ A)
{
    const int bt = blockIdx.x >> 4, cq = blockIdx.x & 15;
    const int b = bt >> 2, t = bt & 3;
    const int tid = threadIdx.x;
    __shared__ float As[4][132];
    __shared__ float Zs[64][132];
    #pragma unroll
    for (int it = 0; it < 2; ++it) {
        int e = it * 256 + tid;
        int n = e >> 7, p = e & 127;
        As[n][p] = aw[(size_t)((b * 4 + n) * 4 + t) * 128 + p];
    }
    const int c0 = cq * 64;
    #pragma unroll
    for (int it = 0; it < 8; ++it) {
        int e = (it * 256 + tid) * 4;
        int r = e >> 7, cc = e & 127;
        *(float4*)&Zs[r][cc] = *(const float4*)(z + (size_t)(b * 1024 + c0 + r) * 512 + t * 128 + cc);
    }
    __syncthreads();
    const int cl = tid >> 2, n = tid & 3;
    float acc = 0.f;
    #pragma unroll
    for (int k4 = 0; k4 < 32; ++k4) {
        float4 zv = *(const float4*)&Zs[cl][4 * k4];
        float4 av = *(const float4*)&As[n][4 * k4];
        acc += zv.x * av.x + zv.y * av.y + zv.z * av.z + zv.w * av.w;
    }
    A[(size_t)(b * 16 + t * 4 + n) * 1024 + c0 + cl] = acc;
}

// ---- 9) reduce_dimension: NB[68][512] = A @ g_w^T + g_b --------------------
__global__ __launch_bounds__(256) void k_rd(const float* __restrict__ A, const float* __restrict__ gw,
                                            const float* __restrict__ gb, float* __restrict__ NB)
{
    int flat = blockIdx.x * 256 + threadIdx.x;
    int row = flat >> 9, o = flat & 511;
    const float4* a4 = (const float4*)(A + (size_t)row * 1024);
    const float4* w4 = (const float4*)(gw + (size_t)o * 1024);
    float acc = 0.f;
    for (int k = 0; k < 256; ++k) {
        float4 av = a4[k], wv = w4[k];
        acc += av.x * wv.x + av.y * wv.y + av.z * wv.z + av.w * wv.w;
    }
    NB[flat] = acc + gb[o];
}

// ---- 10) nodes = parts_r + u_r @ wu ; grid 32 -------------------------------
__global__ __launch_bounds__(256) void k_nodes(const float* __restrict__ NB, const float* __restrict__ wu,
                                               float* __restrict__ nodes)
{
    const int b = blockIdx.x >> 3, oc = blockIdx.x & 7;
    const int tid = threadIdx.x;
    __shared__ float us[512];
    __shared__ float part[4][64];
    __shared__ float uwu[64];
    us[tid] = NB[(size_t)(64 + b) * 512 + tid];
    us[tid + 256] = NB[(size_t)(64 + b) * 512 + tid + 256];
    __syncthreads();
    const int ol = tid & 63, qd = tid >> 6;
    const int o = oc * 64 + ol;
    float acc = 0.f;
    for (int k = qd * 128; k < qd * 128 + 128; ++k)
        acc += us[k] * wu[(size_t)k * 512 + o];
    part[qd][ol] = acc;
    __syncthreads();
    if (tid < 64) uwu[tid] = part[0][tid] + part[1][tid] + part[2][tid] + part[3][tid];
    __syncthreads();
    #pragma unroll
    for (int it = 0; it < 4; ++it) {
        int e = it * 256 + tid;
        int j = e >> 6, o2 = e & 63;
        nodes[(size_t)b * 8192 + (size_t)j * 512 + oc * 64 + o2] =
            NB[(size_t)(b * 16 + j) * 512 + oc * 64 + o2] + uwu[o2];
    }
}

// ---- 11) qt/pp/gg = nodes @ {wt,wp,wg} -------------------------------------
__global__ __launch_bounds__(256) void k_qpg(const float* __restrict__ nodes, const float* __restrict__ wt,
                                             const float* __restrict__ wp, const float* __restrict__ wg,
                                             float* __restrict__ qpg)
{
    const int b = blockIdx.x / 12;
    const int r = blockIdx.x % 12;
    const int m = r >> 2;
    const int o0 = (r & 3) * 128;
    const float* W = (m == 0) ? wt : (m == 1) ? wp : wg;
    const int tid = threadIdx.x;
    __shared__ float ns[16][512];
    #pragma unroll
    for (int it = 0; it < 32; ++it) {
        int e = it * 256 + tid;
        ns[e >> 9][e & 511] = nodes[(size_t)b * 8192 + e];
    }
    __syncthreads();
    const int o = o0 + (tid & 127);
    const int jg = tid >> 7;
    float acc[8];
    #pragma unroll
    for (int jj = 0; jj < 8; ++jj) acc[jj] = 0.f;
    for (int k4 = 0; k4 < 128; ++k4) {
        float w0 = W[(size_t)(4 * k4 + 0) * 512 + o];
        float w1 = W[(size_t)(4 * k4 + 1) * 512 + o];
        float w2 = W[(size_t)(4 * k4 + 2) * 512 + o];
        float w3 = W[(size_t)(4 * k4 + 3) * 512 + o];
        #pragma unroll
        for (int jj = 0; jj < 8; ++jj) {
            float4 nv = *(const float4*)&ns[jg * 8 + jj][4 * k4];
            acc[jj] += nv.x * w0 + nv.y * w1 + nv.z * w2 + nv.w * w3;
        }
    }
    #pragma unroll
    for (int jj = 0; jj < 8; ++jj)
        qpg[(size_t)((m * 4 + b) * 16 + jg * 8 + jj) * 512 + o] = acc[jj];
}

// ---- 12) STIAU attention + aggregate + cat ---------------------------------
__global__ __launch_bounds__(256) void k_stiau(const float* __restrict__ nodes, const float* __restrict__ qpg,
                                               const float* __restrict__ NB, float* __restrict__ cat)
{
    const int b = blockIdx.x;
    const int tid = threadIdx.x;
    __shared__ float q_s[16][516];
    __shared__ float p_s[16][516];
    __shared__ float att[16][17];
    #pragma unroll
    for (int it = 0; it < 32; ++it) {
        int e = it * 256 + tid;
        int j = e >> 9, k = e & 511;
        q_s[j][k] = qpg[(size_t)(0 * 4 + b) * 8192 + e];
        p_s[j][k] = qpg[(size_t)(1 * 4 + b) * 8192 + e];
    }
    __syncthreads();
    const int j = tid >> 4, mm = tid & 15;
    float acc = 0.f;
    #pragma unroll
    for (int k4 = 0; k4 < 128; ++k4) {
        float4 qv = *(const float4*)&q_s[j][4 * k4];
        float4 pv = *(const float4*)&p_s[mm][4 * k4];
        acc += qv.x * pv.x + qv.y * pv.y + qv.z * pv.z + qv.w * pv.w;
    }
    acc *= 0.04419417382415922f;
    float mx = acc;
    #pragma unroll
    for (int off = 1; off < 16; off <<= 1) mx = fmaxf(mx, __shfl_xor(mx, off, 64));
    float ev = __expf(acc - mx);
    float sm = ev;
    #pragma unroll
    for (int off = 1; off < 16; off <<= 1) sm += __shfl_xor(sm, off, 64);
    att[j][mm] = ev / sm;
    __syncthreads();
    #pragma unroll
    for (int it = 0; it < 32; ++it) {
        int e = it * 256 + tid;
        q_s[e >> 9][e & 511] = qpg[(size_t)(2 * 4 + b) * 8192 + e];
    }
    __syncthreads();
    #pragma unroll
    for (int it = 0; it < 32; ++it) {
        int e = it * 256 + tid;
        int jj = e >> 9, o = e & 511;
        float v = nodes[(size_t)b * 8192 + e];
        #pragma unroll
        for (int m2 = 0; m2 < 16; ++m2) v += att[jj][m2] * q_s[m2][o];
        p_s[jj][o] = v;
    }
    __syncthreads();
    #pragma unroll
    for (int it = 0; it < 16; ++it) {
        int e = it * 256 + tid;
        int t = e >> 10, cc = e & 1023;
        float val;
        if (cc < 512)
            val = 0.25f * (p_s[t * 4 + 0][cc] + p_s[t * 4 + 1][cc] + p_s[t * 4 + 2][cc] + p_s[t * 4 + 3][cc]);
        else
            val = NB[(size_t)(64 + b) * 512 + (cc - 512)];
        cat[(size_t)(b * 4 + t) * 1024 + cc] = val;
    }
}

// ---- 13) fused w2 + BN + residual: grid 1024 (one block per channel o) ------
__global__ __launch_bounds__(256) void k_w2bn(const float* __restrict__ cat, const float* __restrict__ w2w,
                                              const float* __restrict__ g, const float* __restrict__ beta,
                                              const float* __restrict__ z, float* __restrict__ zout)
{
    const int o = blockIdx.x;
    const int tid = threadIdx.x;
    const int pair = tid >> 4;     // (b,t) 0..15
    const int slice = tid & 15;    // k-chunk of 64
    const int b = pair >> 2, t = pair & 3;
    __shared__ float red[16][17];
    __shared__ float vv[16];
    __shared__ float bnv[16];

    const float4* c4 = (const float4*)(cat + (size_t)(b * 4 + t) * 1024) + slice * 16;
    const float4* w4 = (const float4*)(w2w + (size_t)o * 1024) + slice * 16;
    float acc = 0.f;
    #pragma unroll
    for (int k = 0; k < 16; ++k) {
        float4 cv = c4[k], wv = w4[k];
        acc += cv.x * wv.x + cv.y * wv.y + cv.z * wv.z + cv.w * wv.w;
    }
    red[pair][slice] = acc;
    __syncthreads();
    if (tid < 16) {
        float v = 0.f;
        #pragma unroll
        for (int i = 0; i < 16; ++i) v += red[tid][i];
        vv[tid] = v;
    }
    __syncthreads();
    if (tid < 16) {
        float s = 0.f, q = 0.f;
        #pragma unroll
        for (int i = 0; i < 16; ++i) { float v = vv[i]; s += v; q += v * v; }
        float m = s * (1.f / 16.f);
        float var = q * (1.f / 16.f) - m * m;
        float rs = rsqrtf(var + EPSBN) * g[o];
        bnv[tid] = vv[tid] * rs + (beta[o] - m * rs);
    }
    __syncthreads();
    #pragma unroll
    for (int it = 0; it < 8; ++it) {
        int e = it * 256 + tid;     // bt*128 + p
        int bt = e >> 7, p = e & 127;
        int b2 = bt >> 2, t2 = bt & 3;
        size_t idx = (size_t)(b2 * 1024 + o) * 512 + t2 * 128 + p;
        zout[idx] = z[idx] + bnv[bt];
    }
}

extern "C" void kernel_launch(void* const* d_in, const int* in_sizes, int n_in,
                              void* d_out, int out_size, void* d_ws, size_t ws_size,
                              hipStream_t stream)
{
    const float* x      = (const float*)d_in[0];
    const float* sa_w   = (const float*)d_in[1];
    const float* sa_g   = (const float*)d_in[3];
    const float* sa_be  = (const float*)d_in[4];
    const float* g_w    = (const float*)d_in[5];
    const float* g_b    = (const float*)d_in[6];
    const float* w1_w   = (const float*)d_in[7];
    const float* w1_g   = (const float*)d_in[9];
    const float* w1_be  = (const float*)d_in[10];
    const float* w2_w   = (const float*)d_in[11];
    const float* w2_g   = (const float*)d_in[13];
    const float* w2_be  = (const float*)d_in[14];
    const float* wt     = (const float*)d_in[15];
    const float* wp     = (const float*)d_in[16];
    const float* wg     = (const float*)d_in[17];
    const float* wu     = (const float*)d_in[18];
    float* out = (float*)d_out;
    float* ws  = (float*)d_ws;
    if (ws_size < (size_t)WS_FLOATS * sizeof(float)) return;  // fail loudly

    short* YBF  = (short*)(ws + OFF_Y);
    short* XBF  = (short*)(ws + OFF_Y + 1048576);
    short* WBF  = (short*)(ws + OFF_Z);
    float* Y1   = ws + OFF_Y1;
    float* Z    = ws + OFF_Z;
    float* BN1  = ws + OFF_BN1;
    float* A    = ws + OFF_A;
    float* NBm  = ws + OFF_NB;
    float* NOD  = ws + OFF_NODES;
    float* QPG  = ws + OFF_QPG;
    float* CAT  = ws + OFF_CAT;
    float* AW   = ws + OFF_AW;
    float* SAPART = ws + OFF_Y;
    float* AOUT = out + 2097152;

    hipLaunchKernelGGL(k_prep,      dim3(12296), dim3(256), 0, stream, x, w1_w, XBF, WBF, BN1);
    hipLaunchKernelGGL(k_attn_mfma, dim3(256),   dim3(512), 0, stream, XBF, YBF);
    hipLaunchKernelGGL(k_w1_mfma,   dim3(512),   dim3(256), 0, stream, YBF, WBF, Y1, BN1);
    hipLaunchKernelGGL(k_zu,        dim3(4096),  dim3(128), 0, stream, Y1, x, BN1, w1_g, w1_be, Z, A);
    hipLaunchKernelGGL(k_sap,       dim3(256),   dim3(256), 0, stream, Z, sa_w, SAPART);
    hipLaunchKernelGGL(k_sastat,    dim3(4),     dim3(256), 0, stream, SAPART, sa_g, sa_be, AW, AOUT);
    hipLaunchKernelGGL(k_parts,     dim3(256),   dim3(256), 0, stream, Z, AW, A);
    hipLaunchKernelGGL(k_rd,        dim3(136),   dim3(256), 0, stream, A, g_w, g_b, NBm);
    hipLaunchKernelGGL(k_nodes,     dim3(32),    dim3(256), 0, stream, NBm, wu, NOD);
    hipLaunchKernelGGL(k_qpg,       dim3(48),    dim3(256), 0, stream, NOD, wt, wp, wg, QPG);
    hipLaunchKernelGGL(k_stiau,     dim3(4),     dim3(256), 0, stream, NOD, QPG, NBm, CAT);
    hipLaunchKernelGGL(k_w2bn,      dim3(1024),  dim3(256), 0, stream, CAT, w2_w, w2_g, w2_be, Z, out);
}